// Round 11
// baseline (870.778 us; speedup 1.0000x reference)
//
#include <hip/hip_runtime.h>
#include <hip/hip_bf16.h>

// Problem constants
#define BB   16384
#define NBR  3
#define DD   1024
#define HH   8
#define HDD  128

typedef __attribute__((ext_vector_type(8))) short short8;
typedef __attribute__((ext_vector_type(4))) float f32x4;

__device__ __forceinline__ float b2f(ushort u) {
    union { unsigned int i; float f; } x; x.i = ((unsigned int)u) << 16; return x.f;
}
__device__ __forceinline__ ushort f2b(float f) {
    union { __hip_bfloat16 h; ushort u; } x; x.h = __float2bfloat16(f); return x.u;
}

// ---------------- fp32 -> bf16 convert (x input) ----------------
__global__ __launch_bounds__(256) void cvt_f32_bf16(const float* __restrict__ in,
                                                    ushort* __restrict__ out, long n) {
    long i = ((long)blockIdx.x * 256 + threadIdx.x) * 4;
    if (i + 4 > n) return;
    float4 v = *reinterpret_cast<const float4*>(in + i);
    unsigned int a = ((unsigned int)f2b(v.x)) | (((unsigned int)f2b(v.y)) << 16);
    unsigned int b = ((unsigned int)f2b(v.z)) | (((unsigned int)f2b(v.w)) << 16);
    uint2 p; p.x = a; p.y = b;
    *reinterpret_cast<uint2*>(out + i) = p;
}

// ---------------- fused weight converts (5 segments) + zbias zero ----------------
// zbias lives in the STABLE weight region (never aliased by activations).
__global__ __launch_bounds__(256) void cvt_weights(const float* __restrict__ ipw,
                                                   const float* __restrict__ wg1w,
                                                   const float* __restrict__ wg2w,
                                                   const float* __restrict__ r1w,
                                                   const float* __restrict__ r2w,
                                                   ushort* __restrict__ w_ip,
                                                   ushort* __restrict__ w_g1,
                                                   ushort* __restrict__ w_g2,
                                                   ushort* __restrict__ w_r1,
                                                   ushort* __restrict__ w_r2,
                                                   float* __restrict__ zbias) {
    if (blockIdx.x == 0) {
        float4 z = {0.f, 0.f, 0.f, 0.f};
        ((float4*)zbias)[threadIdx.x] = z;     // 1024 floats
    }
    long idx = (long)blockIdx.x * 256 + threadIdx.x;   // float4 units
    const float* src; ushort* dst;
    if (idx < 786432)                    { src = ipw;  dst = w_ip; }
    else if ((idx -= 786432) < 786432)   { src = wg1w; dst = w_g1; }
    else if ((idx -= 786432) < 131072)   { src = wg2w; dst = w_g2; }
    else if ((idx -= 131072) < 524288)   { src = r1w;  dst = w_r1; }
    else { idx -= 524288; if (idx >= 524288) return; src = r2w; dst = w_r2; }
    float4 v = ((const float4*)src)[idx];
    uint2 p;
    p.x = ((unsigned int)f2b(v.x)) | (((unsigned int)f2b(v.y)) << 16);
    p.y = ((unsigned int)f2b(v.z)) | (((unsigned int)f2b(v.w)) << 16);
    ((uint2*)dst)[idx] = p;
}

// ---------------- fp32 [1024,1024] transpose -> bf16 ----------------
__global__ __launch_bounds__(256) void transpose_cvt(const float* __restrict__ in,
                                                     ushort* __restrict__ out) {
    __shared__ float t[32][33];
    const int bx = blockIdx.x & 31, by = blockIdx.x >> 5;
    const int tx = threadIdx.x & 31, ty = threadIdx.x >> 5;   // 32x8
    #pragma unroll
    for (int i = 0; i < 4; i++)
        t[ty + i * 8][tx] = in[(size_t)(by * 32 + ty + i * 8) * 1024 + bx * 32 + tx];
    __syncthreads();
    #pragma unroll
    for (int i = 0; i < 4; i++)
        out[(size_t)(bx * 32 + ty + i * 8) * 1024 + by * 32 + tx] = f2b(t[tx][ty + i * 8]);
}

// ---------------- b1' = wg1_b + sum_s wg1_w_s @ out_b ----------------
__global__ __launch_bounds__(256) void bias1_kernel(const float* __restrict__ wg1w,
                                                    const float* __restrict__ wg1b,
                                                    const float* __restrict__ outb,
                                                    float* __restrict__ b1p) {
    const int o = (blockIdx.x * 256 + threadIdx.x) >> 6;
    const int lane = threadIdx.x & 63;
    const float* wr = wg1w + (size_t)o * 3072;
    float s = 0.f;
    for (int e = lane; e < 1024; e += 64)
        s += outb[e] * (wr[e] + wr[e + 1024] + wr[e + 2048]);
    #pragma unroll
    for (int off = 32; off; off >>= 1) s += __shfl_xor(s, off, 64);
    if (lane == 0) b1p[o] = s + wg1b[o];
}

// ---------------- b'[o] = sum_k w[o,k]*bin[k] + badd[o]  (one wave per o) ----------------
__global__ __launch_bounds__(256) void biasfold_kernel(const float* __restrict__ w,
                                                       const float* __restrict__ bin,
                                                       const float* __restrict__ badd,
                                                       float* __restrict__ outb, int K) {
    const int o = (blockIdx.x * 256 + threadIdx.x) >> 6;
    const int lane = threadIdx.x & 63;
    const float* wr = w + (size_t)o * K;
    float s = 0.f;
    for (int e = lane; e < K; e += 64) s += bin[e] * wr[e];
    #pragma unroll
    for (int off = 32; off; off >>= 1) s += __shfl_xor(s, off, 64);
    if (lane == 0) outb[o] = s + badd[o];
}

// =====================================================================
// 256x256 GEMM: C[M,N] = A[M,K] @ Bt[N,K]^T + bias
// 512 threads (8 waves, 2x4), BK=64, double-buffered 128KiB LDS,
// staggered prefetch, counted vmcnt(2), raw barriers, XOR-swizzled LDS,
// setprio, XCD swizzle, pipelined ds_reads, LDS-staged epilogue.
// PERSISTENT: grid=256, each block processes G=ntiles/256 output tiles;
// the 8 staging loads of tile g+1 are issued BEFORE the epilogue of
// tile g (into buf0, which is dead), so the next main loop starts warm.
// Epilogue stages C in the two buf1 windows (2x32KB, 2 passes) with a
// row-XOR column swizzle (conflict-free writes, dense 64B global lines).
// EPI: 0 = bf16 out, 1 = bf16 out + relu
// =====================================================================
template<int EPI>
__global__ __launch_bounds__(512, 2)
void gemm256(const ushort* __restrict__ A, const ushort* __restrict__ Bt,
             const float* __restrict__ bias, void* __restrict__ Cout,
             int M, int N, int K, int ntiles) {
    extern __shared__ ushort lds[];   // [A0|A1|B0|B1] 16384 elems each

    const int tid  = threadIdx.x;     // 0..511
    const int wid  = tid >> 6;        // 0..7
    const int lane = tid & 63;
    const int nbn  = N >> 8;
    const int tpx  = ntiles >> 3;     // tiles per XCD
    const int G    = ntiles >> 8;     // tiles per block (grid = 256)
    const int xcd  = blockIdx.x & 7;
    const int kq   = blockIdx.x >> 3; // 0..31

    // ---- staging lane mapping (constant across tiles)
    const int srow = tid >> 3;                         // 0..63
    const int kel  = (((tid & 7) ^ (srow & 7)) << 3);  // pre-swizzled k element offset
    const int widEl = wid * 512;                       // wave-uniform LDS element base

    // ---- fragment read offsets (per lane)
    const int wr = wid >> 2, wc = wid & 3;   // 2x4 waves; per-wave C block 128x64
    const int lm15 = lane & 15;
    int aoff[8];
    #pragma unroll
    for (int m = 0; m < 8; m++) aoff[m] = (wr * 128 + m * 16 + lm15) * 64;
    int boff[4];
    #pragma unroll
    for (int c = 0; c < 4; c++) boff[c] = (wc * 64 + c * 16 + lm15) * 64;
    const int kbr[2] = {
        (((0 << 6) | ((lane >> 4) << 4)) ^ ((lane & 7) << 4)) >> 1,
        (((1 << 6) | ((lane >> 4) << 4)) ^ ((lane & 7) << 4)) >> 1
    };
    const int l16 = lane >> 4;
    const int NT = K >> 6;            // K-tiles (even)

    short8 af[8], af2[8], bf[2], bf2[2];

#define STAGE(C, PB, TT) { \
    const ushort* _g0; const ushort* _g1; int _b; \
    if ((C) < 2) { _g0 = gA[(C)][0] + (TT) * 64; _g1 = gA[(C)][1] + (TT) * 64; \
                   _b = (PB) * 16384 + (C) * 8192 + widEl; } \
    else         { _g0 = gB[(C) - 2][0] + (TT) * 64; _g1 = gB[(C) - 2][1] + (TT) * 64; \
                   _b = 32768 + (PB) * 16384 + ((C) - 2) * 8192 + widEl; } \
    __builtin_amdgcn_global_load_lds((const __attribute__((address_space(1))) void*)_g0, \
        (__attribute__((address_space(3))) void*)&lds[_b], 16, 0, 0); \
    __builtin_amdgcn_global_load_lds((const __attribute__((address_space(1))) void*)_g1, \
        (__attribute__((address_space(3))) void*)&lds[_b + 4096], 16, 0, 0); }

#define READ_A(DST, P, KK) { \
    _Pragma("unroll") \
    for (int _m = 0; _m < 8; _m++) \
        DST[_m] = *(const short8*)&lds[(P) * 16384 + aoff[_m] + kbr[KK]]; }

#define READ_B2(DST, P, KK, C0) { \
    DST[0] = *(const short8*)&lds[32768 + (P) * 16384 + boff[(C0)] + kbr[KK]]; \
    DST[1] = *(const short8*)&lds[32768 + (P) * 16384 + boff[(C0) + 1] + kbr[KK]]; }

#define MFMA8x2(AF, BF, C0) { \
    _Pragma("unroll") \
    for (int _m = 0; _m < 8; _m++) { \
        acc[_m][(C0)]     = __builtin_amdgcn_mfma_f32_16x16x32_bf16(AF[_m], BF[0], acc[_m][(C0)], 0, 0, 0); \
        acc[_m][(C0) + 1] = __builtin_amdgcn_mfma_f32_16x16x32_bf16(AF[_m], BF[1], acc[_m][(C0) + 1], 0, 0, 0); } }

#define TILE_STEP(P, T, PRE) { \
    if (PRE) STAGE(0, (P) ^ 1, (T) + 1); \
    if (PRE) { asm volatile("s_waitcnt vmcnt(2)" ::: "memory"); } \
    else     { asm volatile("s_waitcnt vmcnt(0)" ::: "memory"); } \
    __builtin_amdgcn_s_barrier(); \
    asm volatile("" ::: "memory"); \
    __builtin_amdgcn_sched_barrier(0); \
    READ_A(af, P, 0); \
    READ_B2(bf, P, 0, 0); \
    __builtin_amdgcn_s_setprio(1); MFMA8x2(af, bf, 0); __builtin_amdgcn_s_setprio(0); \
    if (PRE) STAGE(1, (P) ^ 1, (T) + 1); \
    READ_B2(bf2, P, 0, 2); \
    __builtin_amdgcn_s_barrier(); \
    __builtin_amdgcn_s_setprio(1); MFMA8x2(af, bf2, 2); __builtin_amdgcn_s_setprio(0); \
    if (PRE) STAGE(2, (P) ^ 1, (T) + 1); \
    READ_A(af2, P, 1); \
    READ_B2(bf, P, 1, 0); \
    __builtin_amdgcn_s_barrier(); \
    __builtin_amdgcn_s_setprio(1); MFMA8x2(af2, bf, 0); __builtin_amdgcn_s_setprio(0); \
    if (PRE) STAGE(3, (P) ^ 1, (T) + 1); \
    READ_B2(bf2, P, 1, 2); \
    __builtin_amdgcn_s_barrier(); \
    __builtin_amdgcn_s_setprio(1); MFMA8x2(af2, bf2, 2); __builtin_amdgcn_s_setprio(0); \
    __builtin_amdgcn_s_barrier(); }

    for (int g = 0; g < G; ++g) {
        const int bid = xcd * tpx + g * 32 + kq;
        const int bm  = bid / nbn;
        const int bn  = bid % nbn;
        const long m0 = (long)bm * 256;
        const long n0 = (long)bn * 256;

        const ushort* gA[2][2];
        const ushort* gB[2][2];
        #pragma unroll
        for (int c = 0; c < 2; c++)
            #pragma unroll
            for (int j = 0; j < 2; j++) {
                gA[c][j] = A  + (size_t)(m0 + c * 128 + j * 64 + srow) * K + kel;
                gB[c][j] = Bt + (size_t)(n0 + c * 128 + j * 64 + srow) * K + kel;
            }

        f32x4 acc[8][4];
        #pragma unroll
        for (int m = 0; m < 8; m++)
            #pragma unroll
            for (int c = 0; c < 4; c++) { f32x4 z = {0.f, 0.f, 0.f, 0.f}; acc[m][c] = z; }

        if (g == 0) {   // cold prologue (g>0: tile 0 prefetched during prior epilogue)
            STAGE(0, 0, 0); STAGE(1, 0, 0); STAGE(2, 0, 0); STAGE(3, 0, 0);
        }

        int t = 0;
        for (; t + 2 < NT; t += 2) {
            TILE_STEP(0, t, true);
            TILE_STEP(1, t + 1, true);
        }
        TILE_STEP(0, t, true);
        TILE_STEP(1, t + 1, false);

        // ---- prefetch next output tile's K-tile 0 into buf0 (dead), before epilogue ----
        if (g + 1 < G) {
            const int bid2 = xcd * tpx + (g + 1) * 32 + kq;
            const int bm2  = bid2 / nbn;
            const int bn2  = bid2 % nbn;
            const long m02 = (long)bm2 * 256;
            const long n02 = (long)bn2 * 256;
            #pragma unroll
            for (int c = 0; c < 2; c++)
                #pragma unroll
                for (int j = 0; j < 2; j++) {
                    const ushort* a2 = A  + (size_t)(m02 + c * 128 + j * 64 + srow) * K + kel;
                    const ushort* b2 = Bt + (size_t)(n02 + c * 128 + j * 64 + srow) * K + kel;
                    __builtin_amdgcn_global_load_lds(
                        (const __attribute__((address_space(1))) void*)a2,
                        (__attribute__((address_space(3))) void*)&lds[c * 8192 + j * 4096 + widEl],
                        16, 0, 0);
                    __builtin_amdgcn_global_load_lds(
                        (const __attribute__((address_space(1))) void*)b2,
                        (__attribute__((address_space(3))) void*)&lds[32768 + c * 8192 + j * 4096 + widEl],
                        16, 0, 0);
                }
        }

        // ---- epilogue via buf1 windows: CA = A-buf1, CB = B-buf1 (64 rows x 256 each) ----
        #pragma unroll
        for (int s = 0; s < 2; ++s) {
            const int cbase = wr ? 49152 : 16384;
            #pragma unroll
            for (int c = 0; c < 4; c++) {
                const int colc = wc * 64 + c * 16 + lm15;
                const float bc = bias[n0 + colc];
                #pragma unroll
                for (int mm = 0; mm < 4; mm++) {
                    const int m = s * 4 + mm;
                    #pragma unroll
                    for (int j = 0; j < 4; j++) {
                        const int srw = mm * 16 + l16 * 4 + j;       // 0..63
                        float v = acc[m][c][j] + bc;
                        if (EPI == 1) v = v > 0.f ? v : 0.f;
                        const int scol = colc ^ (((srw >> 2) & 3) << 4);
                        lds[cbase + srw * 256 + scol] = f2b(v);
                    }
                }
            }
            __syncthreads();
            {
                const int r0 = tid >> 5;          // 0..15
                const int c0 = (tid & 31) * 8;    // 0..248
                #pragma unroll
                for (int it = 0; it < 8; it++) {
                    const int slot = it * 16 + r0;                   // 0..127
                    const int srw  = slot & 63;
                    const int base = (slot < 64) ? 16384 : 49152;
                    const int scol = c0 ^ (((srw >> 2) & 3) << 4);
                    short8 val = *(const short8*)&lds[base + srw * 256 + scol];
                    const long grow = m0 + 64 * s + slot + ((slot >> 6) << 6);
                    *reinterpret_cast<short8*>(&((ushort*)Cout)[grow * (long)N + n0 + c0]) = val;
                }
            }
            __syncthreads();
        }
    }

#undef TILE_STEP
#undef MFMA8x2
#undef READ_B2
#undef READ_A
#undef STAGE
}

// ---------------- 128x128 bf16 GEMM with lda/ldb/ldc + batch (blockIdx.y) ----------------
template<int EPI>
__global__ __launch_bounds__(256, 2)
void gemm_bt(const ushort* __restrict__ A, const ushort* __restrict__ Bt,
             const float* __restrict__ bias, void* __restrict__ Cout,
             int M, int N, int K, int lda, int ldb, int ldc, int sA, int sC) {
    __shared__ ushort As[128 * 64];
    __shared__ ushort Bs[128 * 64];
    const int tid  = threadIdx.x;
    const int wid  = tid >> 6;
    const int lane = tid & 63;
    const int cpx  = gridDim.x >> 3;
    const int bid  = (blockIdx.x & 7) * cpx + (blockIdx.x >> 3);
    const int nbn  = N >> 7;
    const int bm   = bid / nbn;
    const int bn   = bid % nbn;
    const long m0  = (long)bm * 128;
    const long n0  = (long)bn * 128;

    A += (size_t)blockIdx.y * sA;
    const long cOff = (long)blockIdx.y * sC;

    const int srow = tid >> 3;
    const int scol = (tid & 7) << 3;
    const ushort* gA = A  + (m0 + srow) * (long)lda + scol;
    const ushort* gB = Bt + (n0 + srow) * (long)ldb + scol;

    f32x4 acc[4][4];
    #pragma unroll
    for (int i = 0; i < 4; i++)
        #pragma unroll
        for (int j = 0; j < 4; j++) { f32x4 z = {0.f, 0.f, 0.f, 0.f}; acc[i][j] = z; }

    const int wr = wid >> 1, wc = wid & 1;
    const int kits = K >> 6;

    for (int kt = 0; kt < kits; ++kt) {
        const ushort* pA = gA + kt * 64;
        const ushort* pB = gB + kt * 64;
        #pragma unroll
        for (int i = 0; i < 4; i++) {
            __builtin_amdgcn_global_load_lds(
                (const __attribute__((address_space(1))) void*)(pA + (long)i * 32 * lda),
                (__attribute__((address_space(3))) void*)&As[(i * 32 + wid * 8) * 64],
                16, 0, 0);
        }
        #pragma unroll
        for (int i = 0; i < 4; i++) {
            __builtin_amdgcn_global_load_lds(
                (const __attribute__((address_space(1))) void*)(pB + (long)i * 32 * ldb),
                (__attribute__((address_space(3))) void*)&Bs[(i * 32 + wid * 8) * 64],
                16, 0, 0);
        }
        __syncthreads();
        #pragma unroll
        for (int kk = 0; kk < 2; kk++) {
            const int ko = kk * 32 + (lane >> 4) * 8;
            short8 af[4], bf[4];
            #pragma unroll
            for (int m = 0; m < 4; m++)
                af[m] = *(const short8*)&As[(wr * 64 + m * 16 + (lane & 15)) * 64 + ko];
            #pragma unroll
            for (int n = 0; n < 4; n++)
                bf[n] = *(const short8*)&Bs[(wc * 64 + n * 16 + (lane & 15)) * 64 + ko];
            #pragma unroll
            for (int m = 0; m < 4; m++)
                #pragma unroll
                for (int n = 0; n < 4; n++)
                    acc[m][n] = __builtin_amdgcn_mfma_f32_16x16x32_bf16(af[m], bf[n], acc[m][n], 0, 0, 0);
        }
        __syncthreads();
    }

    #pragma unroll
    for (int n = 0; n < 4; n++) {
        const long c = n0 + wc * 64 + n * 16 + (lane & 15);
        const float bc = bias[c];
        #pragma unroll
        for (int m = 0; m < 4; m++) {
            const long r = m0 + wr * 64 + m * 16 + (lane >> 4) * 4;
            #pragma unroll
            for (int j = 0; j < 4; j++) {
                float v = acc[m][n][j] + bc;
                if (EPI == 1) v = v > 0.f ? v : 0.f;
                ((ushort*)Cout)[(r + j) * (long)ldc + cOff + c] = f2b(v);
            }
        }
    }
}

// ---------------- tiny attention over NB=3 tokens, ONE WAVE per (b,h) ----------------
__global__ __launch_bounds__(256) void attn_kernel(const ushort* __restrict__ qkv,
                                                   ushort* __restrict__ o) {
    const int w    = (blockIdx.x * 256 + threadIdx.x) >> 6;
    const int lane = threadIdx.x & 63;
    const int b = w >> 3, h = w & 7;
    const ushort* base = qkv + (size_t)b * (3 * 3072) + h * HDD + lane * 2;

    float q[3][2], k[3][2], v[3][2];
    #pragma unroll
    for (int i = 0; i < 3; i++) {
        unsigned int qu = *(const unsigned int*)(base + i * 3072);
        unsigned int ku = *(const unsigned int*)(base + i * 3072 + 1024);
        unsigned int vu = *(const unsigned int*)(base + i * 3072 + 2048);
        q[i][0] = b2f((ushort)(qu & 0xffff)); q[i][1] = b2f((ushort)(qu >> 16));
        k[i][0] = b2f((ushort)(ku & 0xffff)); k[i][1] = b2f((ushort)(ku >> 16));
        v[i][0] = b2f((ushort)(vu & 0xffff)); v[i][1] = b2f((ushort)(vu >> 16));
    }

    float s[3][3];
    #pragma unroll
    for (int i = 0; i < 3; i++)
        #pragma unroll
        for (int j = 0; j < 3; j++)
            s[i][j] = q[i][0] * k[j][0] + q[i][1] * k[j][1];

    #pragma unroll
    for (int off = 32; off; off >>= 1)
        #pragma unroll
        for (int i = 0; i < 3; i++)
            #pragma unroll
            for (int j = 0; j < 3; j++)
                s[i][j] += __shfl_xor(s[i][j], off, 64);

    const float sc = 0.08838834764831845f;
    float a[3][3];
    #pragma unroll
    for (int i = 0; i < 3; i++) {
        float l0 = s[i][0] * sc, l1 = s[i][1] * sc, l2 = s[i][2] * sc;
        float mx = fmaxf(fmaxf(l0, l1), l2);
        float e0 = __expf(l0 - mx), e1 = __expf(l1 - mx), e2 = __expf(l2 - mx);
        float inv = 1.f / (e0 + e1 + e2);
        a[i][0] = e0 * inv; a[i][1] = e1 * inv; a[i][2] = e2 * inv;
    }

    ushort* ob = o + (size_t)b * 3072 + h * HDD + lane * 2;
    #pragma unroll
    for (int i = 0; i < 3; i++) {
        float o0 = a[i][0] * v[0][0] + a[i][1] * v[1][0] + a[i][2] * v[2][0];
        float o1 = a[i][0] * v[0][1] + a[i][1] * v[1][1] + a[i][2] * v[2][1];
        unsigned int pk = ((unsigned int)f2b(o0)) | (((unsigned int)f2b(o1)) << 16);
        *(unsigned int*)(ob + i * 1024) = pk;
    }
}

// ---------------- wg3 logits + softmax + weighted branch sum (over o) ----------------
__global__ __launch_bounds__(256) void gate_kernel(const ushort* __restrict__ h2,
                                                   const float* __restrict__ w3,
                                                   const float* __restrict__ b3,
                                                   const ushort* __restrict__ att,
                                                   ushort* __restrict__ weighted) {
    const int gw = (blockIdx.x * 256 + threadIdx.x) >> 6;
    const int lane = threadIdx.x & 63;
    if (gw >= BB) return;

    const ushort* hr = h2 + (size_t)gw * 512 + lane * 8;
    short8 hv = *(const short8*)hr;
    float hf[8];
    #pragma unroll
    for (int d = 0; d < 8; d++) hf[d] = b2f((ushort)hv[d]);

    float dot[3];
    #pragma unroll
    for (int s = 0; s < 3; s++) {
        const float* wr = w3 + s * 512 + lane * 8;
        float4 wa = *(const float4*)wr;
        float4 wb = *(const float4*)(wr + 4);
        dot[s] = hf[0] * wa.x + hf[1] * wa.y + hf[2] * wa.z + hf[3] * wa.w
               + hf[4] * wb.x + hf[5] * wb.y + hf[6] * wb.z + hf[7] * wb.w;
    }
    #pragma unroll
    for (int off = 32; off; off >>= 1)
        #pragma unroll
        for (int s = 0; s < 3; s++) dot[s] += __shfl_xor(dot[s], off, 64);

    float l0 = dot[0] + b3[0], l1 = dot[1] + b3[1], l2 = dot[2] + b3[2];
    float mx = fmaxf(fmaxf(l0, l1), l2);
    float e0 = __expf(l0 - mx), e1 = __expf(l1 - mx), e2 = __expf(l2 - mx);
    float inv = 1.f / (e0 + e1 + e2);
    float w0 = e0 * inv, w1 = e1 * inv, w2 = e2 * inv;

    const ushort* ab = att + (size_t)gw * 3072;
    ushort* wb = weighted + (size_t)gw * 1024;
    #pragma unroll
    for (int i = 0; i < 2; i++) {
        int d0 = (i * 64 + lane) * 8;
        short8 a0 = *(const short8*)(ab + d0);
        short8 a1 = *(const short8*)(ab + 1024 + d0);
        short8 a2 = *(const short8*)(ab + 2048 + d0);
        short8 r;
        #pragma unroll
        for (int d = 0; d < 8; d++) {
            float v = w0 * b2f((ushort)a0[d]) + w1 * b2f((ushort)a1[d]) + w2 * b2f((ushort)a2[d]);
            r[d] = (short)f2b(v);
        }
        *(short8*)(wb + d0) = r;
    }
}

// ---------------- LayerNorm over W cols (bf16 input), one block per row ----------------
template<int W, int RELU, int OUTBF16>
__global__ __launch_bounds__(256) void ln_kernel(const ushort* __restrict__ in,
                                                 const float* __restrict__ g,
                                                 const float* __restrict__ bt,
                                                 void* __restrict__ out) {
    constexpr int E = W / 256;
    const int row = blockIdx.x;
    const ushort* xr = in + (size_t)row * W + threadIdx.x * E;

    float v[E];
    if (E == 8) {
        uint4 raw = *reinterpret_cast<const uint4*>(xr);
        const unsigned int* rw = (const unsigned int*)&raw;
        #pragma unroll
        for (int p = 0; p < 4; p++) {
            v[2 * p]     = b2f((ushort)(rw[p] & 0xffff));
            v[2 * p + 1] = b2f((ushort)(rw[p] >> 16));
        }
    } else {
        uint2 raw = *reinterpret_cast<const uint2*>(xr);
        const unsigned int* rw = (const unsigned int*)&raw;
        #pragma unroll
        for (int p = 0; p < 2; p++) {
            v[2 * p]     = b2f((ushort)(rw[p] & 0xffff));
            v[2 * p + 1] = b2f((ushort)(rw[p] >> 16));
        }
    }

    float s = 0.f;
    #pragma unroll
    for (int e = 0; e < E; e++) s += v[e];

    __shared__ float red1[4], red2[4];
    const int wid = threadIdx.x >> 6, lane = threadIdx.x & 63;
    #pragma unroll
    for (int off = 32; off; off >>= 1) s += __shfl_xor(s, off, 64);
    if (lane == 0) red1[wid] = s;
    __syncthreads();
    const float mean = (red1[0] + red1[1] + red1[2] + red1[3]) / (float)W;

    float q = 0.f;
    #pragma unroll
    for (int e = 0; e < E; e++) { float d = v[e] - mean; q += d * d; }
    #pragma unroll
    for (int off = 32; off; off >>= 1) q += __shfl_xor(q, off, 64);
    if (lane == 0) red2[wid] = q;
    __syncthreads();
    const float var = (red2[0] + red2[1] + red2[2] + red2[3]) / (float)W;
    const float rstd = rsqrtf(var + 1e-5f);

    const int c0 = threadIdx.x * E;
    float o[E];
    #pragma unroll
    for (int e = 0; e < E; e++) {
        float ov = (v[e] - mean) * rstd * g[c0 + e] + bt[c0 + e];
        if (RELU) ov = ov > 0.f ? ov : 0.f;
        o[e] = ov;
    }
    if (OUTBF16) {
        ushort* op = (ushort*)out + (size_t)row * W + c0;
        unsigned int pk[E / 2];
        #pragma unroll
        for (int p = 0; p < E / 2; p++)
            pk[p] = ((unsigned int)f2b(o[2 * p])) | (((unsigned int)f2b(o[2 * p + 1])) << 16);
        if (E == 8) *reinterpret_cast<uint4*>(op) = *(uint4*)pk;
        else        *reinterpret_cast<uint2*>(op) = *(uint2*)pk;
    } else {
        float* op = (float*)out + (size_t)row * W + c0;
        #pragma unroll
        for (int p = 0; p < E / 4; p++)
            reinterpret_cast<float4*>(op)[p] = ((float4*)o)[p];
    }
}

extern "C" void kernel_launch(void* const* d_in, const int* in_sizes, int n_in,
                              void* d_out, int out_size, void* d_ws, size_t ws_size,
                              hipStream_t stream) {
    const float* x    = (const float*)d_in[0];
    const float* ipw  = (const float*)d_in[1];
    const float* ipb  = (const float*)d_in[2];
    const float* outw = (const float*)d_in[3];
    const float* outb = (const float*)d_in[4];
    const float* wg1w = (const float*)d_in[5];
    const float* wg1b = (const float*)d_in[6];
    const float* wg2w = (const float*)d_in[7];
    const float* wg2b = (const float*)d_in[8];
    const float* wg3w = (const float*)d_in[9];
    const float* wg3b = (const float*)d_in[10];
    const float* r1w  = (const float*)d_in[11];
    const float* r1b  = (const float*)d_in[12];
    const float* ln1g = (const float*)d_in[13];
    const float* ln1b = (const float*)d_in[14];
    const float* r2w  = (const float*)d_in[15];
    const float* r2b  = (const float*)d_in[16];
    const float* ln2g = (const float*)d_in[17];
    const float* ln2b = (const float*)d_in[18];

    char* ws = (char*)d_ws;
    // STABLE weight region (never aliased by activations):
    ushort* w_ip  = (ushort*)(ws + 0);          // 3072x1024 bf16 (6 MB)
    float*  zbias = (float*) (ws + 6291456);    // 4 KB (in former w_out gap)
    float*  b1p   = (float*) (ws + 6295552);    // 4 KB
    float*  b_r1c = (float*) (ws + 6299648);    // 8 KB
    ushort* w_g1  = (ushort*)(ws + 8388608);    // 1024x3072
    ushort* w_g2  = (ushort*)(ws + 14680064);   // 512x1024
    ushort* w_r1  = (ushort*)(ws + 15728640);   // 2048x1024
    ushort* w_r2  = (ushort*)(ws + 19922944);   // 1024x2048
    char* R1 = ws + 24117248;                   // 100.7 MB: xb -> o_att -> ln1out
    char* R2 = ws + 124780544;                  // qkv -> subdivided (post-attention)

    ushort* xb       = (ushort*)R1;
    ushort* qkv      = (ushort*)R2;
    ushort* o_att    = (ushort*)R1;                    // [16384, 3072] == o_flat
    ushort* h1       = (ushort*)(R2 + 0);              // 33.5 MB
    ushort* h2       = (ushort*)(R2 + 33554432);       // 16.8 MB
    ushort* wsum_o   = (ushort*)(R2 + 50331648);       // 33.5 MB  (gated sum of o)
    ushort* r1out    = (ushort*)(R2 + 117440512);      // 67 MB
    ushort* r2out    = (ushort*)(R2 + 184549376);      // 33.5 MB
    ushort* w1p      = (ushort*)(R2 + 218103808);      // 6.3 MB  W1' [1024,3072]
    ushort* w_outT   = (ushort*)(R2 + 224395264);      // 2.1 MB  out_w^T bf16
    ushort* w_r1c    = (ushort*)(R2 + 226500608);      // 4.2 MB  (r1_w@out_w) [2048,1024]
    ushort* ln1out   = (ushort*)R1;                    // overwrites o_att (dead)

    const int ldsBytes = 131072;
    (void)hipFuncSetAttribute((const void*)gemm256<0>, hipFuncAttributeMaxDynamicSharedMemorySize, ldsBytes);
    (void)hipFuncSetAttribute((const void*)gemm256<1>, hipFuncAttributeMaxDynamicSharedMemorySize, ldsBytes);

    // converts: x (big) + fused weight converts (also zeros zbias, in stable region)
    cvt_f32_bf16<<<49152, 256, 0, stream>>>(x, xb, (long)49152 * 1024);
    cvt_weights<<<10752, 256, 0, stream>>>(ipw, wg1w, wg2w, r1w, r2w,
                                           w_ip, w_g1, w_g2, w_r1, w_r2, zbias);

    // QKV + attention
    gemm256<0><<<256, 512, ldsBytes, stream>>>(xb, w_ip, ipb, qkv, 49152, 3072, 1024, 2304);
    attn_kernel<<<32768, 256, 0, stream>>>(qkv, o_att);

    // ---- weight prep for folded paths (qkv region now dead) ----
    transpose_cvt<<<1024, 256, 0, stream>>>(outw, w_outT);
    gemm_bt<0><<<dim3(64, 3), 256, 0, stream>>>(w_g1, w_outT, zbias, w1p,
                                                1024, 1024, 1024, 3072, 1024, 3072, 1024, 1024);
    bias1_kernel<<<256, 256, 0, stream>>>(wg1w, wg1b, outb, b1p);
    gemm_bt<0><<<dim3(128, 1), 256, 0, stream>>>(w_r1, w_outT, zbias, w_r1c,
                                                 2048, 1024, 1024, 1024, 1024, 1024, 0, 0);
    biasfold_kernel<<<512, 256, 0, stream>>>(r1w, outb, r1b, b_r1c, 1024);

    // gate MLP on o directly: h1 = relu(o_flat @ W1'^T + b1')
    gemm256<1><<<256, 512, ldsBytes, stream>>>(o_att, w1p, b1p, h1, 16384, 1024, 3072, 256);
    gemm_bt<1><<<dim3(128 * 4, 1), 256, 0, stream>>>(h1, w_g2, wg2b, h2,
                                                     16384, 512, 1024, 1024, 1024, 512, 0, 0);
    gate_kernel<<<4096, 256, 0, stream>>>(h2, wg3w, wg3b, o_att, wsum_o);

    // refiner with folded out-proj: r1out = wsum_o @ (r1_w@out_w)^T + b_r1c
    gemm256<0><<<256, 512, ldsBytes, stream>>>(wsum_o, w_r1c, b_r1c, r1out, 16384, 2048, 1024, 512);
    ln_kernel<2048, 1, 1><<<16384, 256, 0, stream>>>(r1out, ln1g, ln1b, ln1out);
    gemm256<0><<<256, 512, ldsBytes, stream>>>(ln1out, w_r2, r2b, r2out, 16384, 1024, 2048, 256);
    ln_kernel<1024, 0, 0><<<16384, 256, 0, stream>>>(r2out, ln2g, ln2b, d_out);
}

// Round 12
// 826.671 us; speedup vs baseline: 1.0534x; 1.0534x over previous
//
#include <hip/hip_runtime.h>
#include <hip/hip_bf16.h>

// Problem constants
#define BB   16384
#define NBR  3
#define DD   1024
#define HH   8
#define HDD  128

typedef __attribute__((ext_vector_type(8))) short short8;
typedef __attribute__((ext_vector_type(4))) float f32x4;

__device__ __forceinline__ float b2f(ushort u) {
    union { unsigned int i; float f; } x; x.i = ((unsigned int)u) << 16; return x.f;
}
__device__ __forceinline__ ushort f2b(float f) {
    union { __hip_bfloat16 h; ushort u; } x; x.h = __float2bfloat16(f); return x.u;
}

// ---------------- fp32 -> bf16 convert (x input) ----------------
__global__ __launch_bounds__(256) void cvt_f32_bf16(const float* __restrict__ in,
                                                    ushort* __restrict__ out, long n) {
    long i = ((long)blockIdx.x * 256 + threadIdx.x) * 4;
    if (i + 4 > n) return;
    float4 v = *reinterpret_cast<const float4*>(in + i);
    unsigned int a = ((unsigned int)f2b(v.x)) | (((unsigned int)f2b(v.y)) << 16);
    unsigned int b = ((unsigned int)f2b(v.z)) | (((unsigned int)f2b(v.w)) << 16);
    uint2 p; p.x = a; p.y = b;
    *reinterpret_cast<uint2*>(out + i) = p;
}

// ---------------- fused weight converts (5 segments) + zbias zero ----------------
// zbias lives in the STABLE weight region (never aliased by activations).
__global__ __launch_bounds__(256) void cvt_weights(const float* __restrict__ ipw,
                                                   const float* __restrict__ wg1w,
                                                   const float* __restrict__ wg2w,
                                                   const float* __restrict__ r1w,
                                                   const float* __restrict__ r2w,
                                                   ushort* __restrict__ w_ip,
                                                   ushort* __restrict__ w_g1,
                                                   ushort* __restrict__ w_g2,
                                                   ushort* __restrict__ w_r1,
                                                   ushort* __restrict__ w_r2,
                                                   float* __restrict__ zbias) {
    if (blockIdx.x == 0) {
        float4 z = {0.f, 0.f, 0.f, 0.f};
        ((float4*)zbias)[threadIdx.x] = z;     // 1024 floats
    }
    long idx = (long)blockIdx.x * 256 + threadIdx.x;   // float4 units
    const float* src; ushort* dst;
    if (idx < 786432)                    { src = ipw;  dst = w_ip; }
    else if ((idx -= 786432) < 786432)   { src = wg1w; dst = w_g1; }
    else if ((idx -= 786432) < 131072)   { src = wg2w; dst = w_g2; }
    else if ((idx -= 131072) < 524288)   { src = r1w;  dst = w_r1; }
    else { idx -= 524288; if (idx >= 524288) return; src = r2w; dst = w_r2; }
    float4 v = ((const float4*)src)[idx];
    uint2 p;
    p.x = ((unsigned int)f2b(v.x)) | (((unsigned int)f2b(v.y)) << 16);
    p.y = ((unsigned int)f2b(v.z)) | (((unsigned int)f2b(v.w)) << 16);
    ((uint2*)dst)[idx] = p;
}

// ---------------- fp32 [1024,1024] transpose -> bf16 ----------------
__global__ __launch_bounds__(256) void transpose_cvt(const float* __restrict__ in,
                                                     ushort* __restrict__ out) {
    __shared__ float t[32][33];
    const int bx = blockIdx.x & 31, by = blockIdx.x >> 5;
    const int tx = threadIdx.x & 31, ty = threadIdx.x >> 5;   // 32x8
    #pragma unroll
    for (int i = 0; i < 4; i++)
        t[ty + i * 8][tx] = in[(size_t)(by * 32 + ty + i * 8) * 1024 + bx * 32 + tx];
    __syncthreads();
    #pragma unroll
    for (int i = 0; i < 4; i++)
        out[(size_t)(bx * 32 + ty + i * 8) * 1024 + by * 32 + tx] = f2b(t[tx][ty + i * 8]);
}

// ---------------- b1' = wg1_b + sum_s wg1_w_s @ out_b ----------------
__global__ __launch_bounds__(256) void bias1_kernel(const float* __restrict__ wg1w,
                                                    const float* __restrict__ wg1b,
                                                    const float* __restrict__ outb,
                                                    float* __restrict__ b1p) {
    const int o = (blockIdx.x * 256 + threadIdx.x) >> 6;
    const int lane = threadIdx.x & 63;
    const float* wr = wg1w + (size_t)o * 3072;
    float s = 0.f;
    for (int e = lane; e < 1024; e += 64)
        s += outb[e] * (wr[e] + wr[e + 1024] + wr[e + 2048]);
    #pragma unroll
    for (int off = 32; off; off >>= 1) s += __shfl_xor(s, off, 64);
    if (lane == 0) b1p[o] = s + wg1b[o];
}

// ---------------- b'[o] = sum_k w[o,k]*bin[k] + badd[o]  (one wave per o) ----------------
__global__ __launch_bounds__(256) void biasfold_kernel(const float* __restrict__ w,
                                                       const float* __restrict__ bin,
                                                       const float* __restrict__ badd,
                                                       float* __restrict__ outb, int K) {
    const int o = (blockIdx.x * 256 + threadIdx.x) >> 6;
    const int lane = threadIdx.x & 63;
    const float* wr = w + (size_t)o * K;
    float s = 0.f;
    for (int e = lane; e < K; e += 64) s += bin[e] * wr[e];
    #pragma unroll
    for (int off = 32; off; off >>= 1) s += __shfl_xor(s, off, 64);
    if (lane == 0) outb[o] = s + badd[o];
}

// =====================================================================
// 256x256 GEMM: C[M,N] = A[M,K] @ Bt[N,K]^T + bias
// 512 threads (8 waves, 2x4), BK=64, double-buffered 128KiB LDS,
// staggered prefetch, counted vmcnt(2), raw barriers, XOR-swizzled LDS,
// setprio, XCD swizzle, LDS-staged epilogue (dense 64B C-lines),
// ds_reads software-pipelined one phase ahead.
// (Round-8 structure — the persistent variant measured slower.)
// EPI: 0 = bf16 out, 1 = bf16 out + relu
// =====================================================================
#define CPAD 258
template<int EPI>
__global__ __launch_bounds__(512, 2)
void gemm256(const ushort* __restrict__ A, const ushort* __restrict__ Bt,
             const float* __restrict__ bias, void* __restrict__ Cout,
             int M, int N, int K) {
    extern __shared__ ushort lds[];   // main loop: 4x16384; epilogue: [256][258] C tile

    const int tid  = threadIdx.x;     // 0..511
    const int wid  = tid >> 6;        // 0..7
    const int lane = tid & 63;
    // XCD-aware bijective swizzle (grid always divisible by 8)
    const int cpx  = gridDim.x >> 3;
    const int bid  = (blockIdx.x & 7) * cpx + (blockIdx.x >> 3);
    const int nbn  = N >> 8;
    const int bm   = bid / nbn;
    const int bn   = bid % nbn;
    const long m0  = (long)bm * 256;
    const long n0  = (long)bn * 256;
    const int NT   = K >> 6;          // K-tiles (even: 16/32/48)

    // ---- staging addresses
    const int srow = tid >> 3;                         // 0..63
    const int kel  = (((tid & 7) ^ (srow & 7)) << 3);  // pre-swizzled k element offset
    const int widEl = wid * 512;                       // wave-uniform LDS element base

    const ushort* gA[2][2];
    const ushort* gB[2][2];
    #pragma unroll
    for (int c = 0; c < 2; c++)
        #pragma unroll
        for (int j = 0; j < 2; j++) {
            gA[c][j] = A  + (size_t)(m0 + c * 128 + j * 64 + srow) * K + kel;
            gB[c][j] = Bt + (size_t)(n0 + c * 128 + j * 64 + srow) * K + kel;
        }

    // ---- fragment read offsets (per lane)
    const int wr = wid >> 2, wc = wid & 3;   // 2x4 waves; per-wave C block 128x64
    const int lm15 = lane & 15;
    int aoff[8];
    #pragma unroll
    for (int m = 0; m < 8; m++) aoff[m] = (wr * 128 + m * 16 + lm15) * 64;
    int boff[4];
    #pragma unroll
    for (int c = 0; c < 4; c++) boff[c] = (wc * 64 + c * 16 + lm15) * 64;
    const int kbr[2] = {
        (((0 << 6) | ((lane >> 4) << 4)) ^ ((lane & 7) << 4)) >> 1,
        (((1 << 6) | ((lane >> 4) << 4)) ^ ((lane & 7) << 4)) >> 1
    };

    f32x4 acc[8][4];
    #pragma unroll
    for (int m = 0; m < 8; m++)
        #pragma unroll
        for (int c = 0; c < 4; c++) { f32x4 z = {0.f, 0.f, 0.f, 0.f}; acc[m][c] = z; }

    short8 af[8], af2[8], bf[2], bf2[2];

#define STAGE(C, PB, TT) { \
    const ushort* _g0; const ushort* _g1; int _b; \
    if ((C) < 2) { _g0 = gA[(C)][0] + (TT) * 64; _g1 = gA[(C)][1] + (TT) * 64; \
                   _b = (PB) * 16384 + (C) * 8192 + widEl; } \
    else         { _g0 = gB[(C) - 2][0] + (TT) * 64; _g1 = gB[(C) - 2][1] + (TT) * 64; \
                   _b = 32768 + (PB) * 16384 + ((C) - 2) * 8192 + widEl; } \
    __builtin_amdgcn_global_load_lds((const __attribute__((address_space(1))) void*)_g0, \
        (__attribute__((address_space(3))) void*)&lds[_b], 16, 0, 0); \
    __builtin_amdgcn_global_load_lds((const __attribute__((address_space(1))) void*)_g1, \
        (__attribute__((address_space(3))) void*)&lds[_b + 4096], 16, 0, 0); }

#define READ_A(DST, P, KK) { \
    _Pragma("unroll") \
    for (int _m = 0; _m < 8; _m++) \
        DST[_m] = *(const short8*)&lds[(P) * 16384 + aoff[_m] + kbr[KK]]; }

#define READ_B2(DST, P, KK, C0) { \
    DST[0] = *(const short8*)&lds[32768 + (P) * 16384 + boff[(C0)] + kbr[KK]]; \
    DST[1] = *(const short8*)&lds[32768 + (P) * 16384 + boff[(C0) + 1] + kbr[KK]]; }

#define MFMA8x2(AF, BF, C0) { \
    _Pragma("unroll") \
    for (int _m = 0; _m < 8; _m++) { \
        acc[_m][(C0)]     = __builtin_amdgcn_mfma_f32_16x16x32_bf16(AF[_m], BF[0], acc[_m][(C0)], 0, 0, 0); \
        acc[_m][(C0) + 1] = __builtin_amdgcn_mfma_f32_16x16x32_bf16(AF[_m], BF[1], acc[_m][(C0) + 1], 0, 0, 0); } }

// One K-tile: 4 MFMA phases; ds_reads for phase i+1 issued in phase i
// (after its MFMA cluster, before its barrier) so LDS latency hides under
// the barrier wait. Staging: chunk c of tile T+1 issued in phase c.
// Counted vmcnt(2) at tile entry waits exactly this tile's 8 loads.
#define TILE_STEP(P, T, PRE) { \
    if (PRE) STAGE(0, (P) ^ 1, (T) + 1); \
    if (PRE) { asm volatile("s_waitcnt vmcnt(2)" ::: "memory"); } \
    else     { asm volatile("s_waitcnt vmcnt(0)" ::: "memory"); } \
    __builtin_amdgcn_s_barrier(); \
    asm volatile("" ::: "memory"); \
    __builtin_amdgcn_sched_barrier(0); \
    READ_A(af, P, 0); \
    READ_B2(bf, P, 0, 0); \
    __builtin_amdgcn_s_setprio(1); MFMA8x2(af, bf, 0); __builtin_amdgcn_s_setprio(0); \
    if (PRE) STAGE(1, (P) ^ 1, (T) + 1); \
    READ_B2(bf2, P, 0, 2); \
    __builtin_amdgcn_s_barrier(); \
    __builtin_amdgcn_s_setprio(1); MFMA8x2(af, bf2, 2); __builtin_amdgcn_s_setprio(0); \
    if (PRE) STAGE(2, (P) ^ 1, (T) + 1); \
    READ_A(af2, P, 1); \
    READ_B2(bf, P, 1, 0); \
    __builtin_amdgcn_s_barrier(); \
    __builtin_amdgcn_s_setprio(1); MFMA8x2(af2, bf, 0); __builtin_amdgcn_s_setprio(0); \
    if (PRE) STAGE(3, (P) ^ 1, (T) + 1); \
    READ_B2(bf2, P, 1, 2); \
    __builtin_amdgcn_s_barrier(); \
    __builtin_amdgcn_s_setprio(1); MFMA8x2(af2, bf2, 2); __builtin_amdgcn_s_setprio(0); \
    __builtin_amdgcn_s_barrier(); }

    // prologue: stage all of tile 0 into buf0
    STAGE(0, 0, 0); STAGE(1, 0, 0); STAGE(2, 0, 0); STAGE(3, 0, 0);

    int t = 0;
    for (; t + 2 < NT; t += 2) {
        TILE_STEP(0, t, true);
        TILE_STEP(1, t + 1, true);
    }
    TILE_STEP(0, t, true);
    TILE_STEP(1, t + 1, false);

#undef TILE_STEP
#undef MFMA8x2
#undef READ_B2
#undef READ_A
#undef STAGE

    // ---- epilogue via LDS (trailing barrier of last tile guarantees all
    // waves' LDS reads are consumed -> safe to overwrite) ----
    // Fragment layout: row = wr*128 + m*16 + (lane>>4)*4 + j, col = wc*64 + c*16 + (lane&15).
    const int l16 = lane >> 4;
    #pragma unroll
    for (int c = 0; c < 4; c++) {
        const int colc = wc * 64 + c * 16 + lm15;
        const float bc = bias[n0 + colc];
        #pragma unroll
        for (int m = 0; m < 8; m++) {
            const int rowb = wr * 128 + m * 16 + l16 * 4;
            #pragma unroll
            for (int j = 0; j < 4; j++) {
                float v = acc[m][c][j] + bc;
                if (EPI == 1) v = v > 0.f ? v : 0.f;
                lds[(rowb + j) * CPAD + colc] = f2b(v);
            }
        }
    }
    __syncthreads();
    // coalesced copy-out: each wave writes two full 512B row segments per instr
    {
        const int r0 = tid >> 5;          // 0..15
        const int c0 = (tid & 31) * 8;    // 0..248
        #pragma unroll
        for (int it = 0; it < 16; it++) {
            const int row = it * 16 + r0;
            short8 val = *(const short8*)&lds[row * CPAD + c0];
            *reinterpret_cast<short8*>(&((ushort*)Cout)[(m0 + row) * (long)N + n0 + c0]) = val;
        }
    }
}

// ---------------- 128x128 bf16 GEMM with lda/ldb/ldc + batch (blockIdx.y) ----------------
template<int EPI>
__global__ __launch_bounds__(256, 2)
void gemm_bt(const ushort* __restrict__ A, const ushort* __restrict__ Bt,
             const float* __restrict__ bias, void* __restrict__ Cout,
             int M, int N, int K, int lda, int ldb, int ldc, int sA, int sC) {
    __shared__ ushort As[128 * 64];
    __shared__ ushort Bs[128 * 64];
    const int tid  = threadIdx.x;
    const int wid  = tid >> 6;
    const int lane = tid & 63;
    const int cpx  = gridDim.x >> 3;
    const int bid  = (blockIdx.x & 7) * cpx + (blockIdx.x >> 3);
    const int nbn  = N >> 7;
    const int bm   = bid / nbn;
    const int bn   = bid % nbn;
    const long m0  = (long)bm * 128;
    const long n0  = (long)bn * 128;

    A += (size_t)blockIdx.y * sA;
    const long cOff = (long)blockIdx.y * sC;

    const int srow = tid >> 3;
    const int scol = (tid & 7) << 3;
    const ushort* gA = A  + (m0 + srow) * (long)lda + scol;
    const ushort* gB = Bt + (n0 + srow) * (long)ldb + scol;

    f32x4 acc[4][4];
    #pragma unroll
    for (int i = 0; i < 4; i++)
        #pragma unroll
        for (int j = 0; j < 4; j++) { f32x4 z = {0.f, 0.f, 0.f, 0.f}; acc[i][j] = z; }

    const int wr = wid >> 1, wc = wid & 1;
    const int kits = K >> 6;

    for (int kt = 0; kt < kits; ++kt) {
        const ushort* pA = gA + kt * 64;
        const ushort* pB = gB + kt * 64;
        #pragma unroll
        for (int i = 0; i < 4; i++) {
            __builtin_amdgcn_global_load_lds(
                (const __attribute__((address_space(1))) void*)(pA + (long)i * 32 * lda),
                (__attribute__((address_space(3))) void*)&As[(i * 32 + wid * 8) * 64],
                16, 0, 0);
        }
        #pragma unroll
        for (int i = 0; i < 4; i++) {
            __builtin_amdgcn_global_load_lds(
                (const __attribute__((address_space(1))) void*)(pB + (long)i * 32 * ldb),
                (__attribute__((address_space(3))) void*)&Bs[(i * 32 + wid * 8) * 64],
                16, 0, 0);
        }
        __syncthreads();
        #pragma unroll
        for (int kk = 0; kk < 2; kk++) {
            const int ko = kk * 32 + (lane >> 4) * 8;
            short8 af[4], bf[4];
            #pragma unroll
            for (int m = 0; m < 4; m++)
                af[m] = *(const short8*)&As[(wr * 64 + m * 16 + (lane & 15)) * 64 + ko];
            #pragma unroll
            for (int n = 0; n < 4; n++)
                bf[n] = *(const short8*)&Bs[(wc * 64 + n * 16 + (lane & 15)) * 64 + ko];
            #pragma unroll
            for (int m = 0; m < 4; m++)
                #pragma unroll
                for (int n = 0; n < 4; n++)
                    acc[m][n] = __builtin_amdgcn_mfma_f32_16x16x32_bf16(af[m], bf[n], acc[m][n], 0, 0, 0);
        }
        __syncthreads();
    }

    #pragma unroll
    for (int n = 0; n < 4; n++) {
        const long c = n0 + wc * 64 + n * 16 + (lane & 15);
        const float bc = bias[c];
        #pragma unroll
        for (int m = 0; m < 4; m++) {
            const long r = m0 + wr * 64 + m * 16 + (lane >> 4) * 4;
            #pragma unroll
            for (int j = 0; j < 4; j++) {
                float v = acc[m][n][j] + bc;
                if (EPI == 1) v = v > 0.f ? v : 0.f;
                ((ushort*)Cout)[(r + j) * (long)ldc + cOff + c] = f2b(v);
            }
        }
    }
}

// ---------------- tiny attention over NB=3 tokens, ONE WAVE per (b,h) ----------------
__global__ __launch_bounds__(256) void attn_kernel(const ushort* __restrict__ qkv,
                                                   ushort* __restrict__ o) {
    const int w    = (blockIdx.x * 256 + threadIdx.x) >> 6;
    const int lane = threadIdx.x & 63;
    const int b = w >> 3, h = w & 7;
    const ushort* base = qkv + (size_t)b * (3 * 3072) + h * HDD + lane * 2;

    float q[3][2], k[3][2], v[3][2];
    #pragma unroll
    for (int i = 0; i < 3; i++) {
        unsigned int qu = *(const unsigned int*)(base + i * 3072);
        unsigned int ku = *(const unsigned int*)(base + i * 3072 + 1024);
        unsigned int vu = *(const unsigned int*)(base + i * 3072 + 2048);
        q[i][0] = b2f((ushort)(qu & 0xffff)); q[i][1] = b2f((ushort)(qu >> 16));
        k[i][0] = b2f((ushort)(ku & 0xffff)); k[i][1] = b2f((ushort)(ku >> 16));
        v[i][0] = b2f((ushort)(vu & 0xffff)); v[i][1] = b2f((ushort)(vu >> 16));
    }

    float s[3][3];
    #pragma unroll
    for (int i = 0; i < 3; i++)
        #pragma unroll
        for (int j = 0; j < 3; j++)
            s[i][j] = q[i][0] * k[j][0] + q[i][1] * k[j][1];

    #pragma unroll
    for (int off = 32; off; off >>= 1)
        #pragma unroll
        for (int i = 0; i < 3; i++)
            #pragma unroll
            for (int j = 0; j < 3; j++)
                s[i][j] += __shfl_xor(s[i][j], off, 64);

    const float sc = 0.08838834764831845f;
    float a[3][3];
    #pragma unroll
    for (int i = 0; i < 3; i++) {
        float l0 = s[i][0] * sc, l1 = s[i][1] * sc, l2 = s[i][2] * sc;
        float mx = fmaxf(fmaxf(l0, l1), l2);
        float e0 = __expf(l0 - mx), e1 = __expf(l1 - mx), e2 = __expf(l2 - mx);
        float inv = 1.f / (e0 + e1 + e2);
        a[i][0] = e0 * inv; a[i][1] = e1 * inv; a[i][2] = e2 * inv;
    }

    ushort* ob = o + (size_t)b * 3072 + h * HDD + lane * 2;
    #pragma unroll
    for (int i = 0; i < 3; i++) {
        float o0 = a[i][0] * v[0][0] + a[i][1] * v[1][0] + a[i][2] * v[2][0];
        float o1 = a[i][0] * v[0][1] + a[i][1] * v[1][1] + a[i][2] * v[2][1];
        unsigned int pk = ((unsigned int)f2b(o0)) | (((unsigned int)f2b(o1)) << 16);
        *(unsigned int*)(ob + i * 1024) = pk;
    }
}

// ---------------- wg3 logits + softmax + weighted branch sum (over o) ----------------
__global__ __launch_bounds__(256) void gate_kernel(const ushort* __restrict__ h2,
                                                   const float* __restrict__ w3,
                                                   const float* __restrict__ b3,
                                                   const ushort* __restrict__ att,
                                                   ushort* __restrict__ weighted) {
    const int gw = (blockIdx.x * 256 + threadIdx.x) >> 6;
    const int lane = threadIdx.x & 63;
    if (gw >= BB) return;

    const ushort* hr = h2 + (size_t)gw * 512 + lane * 8;
    short8 hv = *(const short8*)hr;
    float hf[8];
    #pragma unroll
    for (int d = 0; d < 8; d++) hf[d] = b2f((ushort)hv[d]);

    float dot[3];
    #pragma unroll
    for (int s = 0; s < 3; s++) {
        const float* wr = w3 + s * 512 + lane * 8;
        float4 wa = *(const float4*)wr;
        float4 wb = *(const float4*)(wr + 4);
        dot[s] = hf[0] * wa.x + hf[1] * wa.y + hf[2] * wa.z + hf[3] * wa.w
               + hf[4] * wb.x + hf[5] * wb.y + hf[6] * wb.z + hf[7] * wb.w;
    }
    #pragma unroll
    for (int off = 32; off; off >>= 1)
        #pragma unroll
        for (int s = 0; s < 3; s++) dot[s] += __shfl_xor(dot[s], off, 64);

    float l0 = dot[0] + b3[0], l1 = dot[1] + b3[1], l2 = dot[2] + b3[2];
    float mx = fmaxf(fmaxf(l0, l1), l2);
    float e0 = __expf(l0 - mx), e1 = __expf(l1 - mx), e2 = __expf(l2 - mx);
    float inv = 1.f / (e0 + e1 + e2);
    float w0 = e0 * inv, w1 = e1 * inv, w2 = e2 * inv;

    const ushort* ab = att + (size_t)gw * 3072;
    ushort* wb = weighted + (size_t)gw * 1024;
    #pragma unroll
    for (int i = 0; i < 2; i++) {
        int d0 = (i * 64 + lane) * 8;
        short8 a0 = *(const short8*)(ab + d0);
        short8 a1 = *(const short8*)(ab + 1024 + d0);
        short8 a2 = *(const short8*)(ab + 2048 + d0);
        short8 r;
        #pragma unroll
        for (int d = 0; d < 8; d++) {
            float v = w0 * b2f((ushort)a0[d]) + w1 * b2f((ushort)a1[d]) + w2 * b2f((ushort)a2[d]);
            r[d] = (short)f2b(v);
        }
        *(short8*)(wb + d0) = r;
    }
}

// ---------------- LayerNorm over W cols (bf16 input), one block per row ----------------
template<int W, int RELU, int OUTBF16>
__global__ __launch_bounds__(256) void ln_kernel(const ushort* __restrict__ in,
                                                 const float* __restrict__ g,
                                                 const float* __restrict__ bt,
                                                 void* __restrict__ out) {
    constexpr int E = W / 256;
    const int row = blockIdx.x;
    const ushort* xr = in + (size_t)row * W + threadIdx.x * E;

    float v[E];
    if (E == 8) {
        uint4 raw = *reinterpret_cast<const uint4*>(xr);
        const unsigned int* rw = (const unsigned int*)&raw;
        #pragma unroll
        for (int p = 0; p < 4; p++) {
            v[2 * p]     = b2f((ushort)(rw[p] & 0xffff));
            v[2 * p + 1] = b2f((ushort)(rw[p] >> 16));
        }
    } else {
        uint2 raw = *reinterpret_cast<const uint2*>(xr);
        const unsigned int* rw = (const unsigned int*)&raw;
        #pragma unroll
        for (int p = 0; p < 2; p++) {
            v[2 * p]     = b2f((ushort)(rw[p] & 0xffff));
            v[2 * p + 1] = b2f((ushort)(rw[p] >> 16));
        }
    }

    float s = 0.f;
    #pragma unroll
    for (int e = 0; e < E; e++) s += v[e];

    __shared__ float red1[4], red2[4];
    const int wid = threadIdx.x >> 6, lane = threadIdx.x & 63;
    #pragma unroll
    for (int off = 32; off; off >>= 1) s += __shfl_xor(s, off, 64);
    if (lane == 0) red1[wid] = s;
    __syncthreads();
    const float mean = (red1[0] + red1[1] + red1[2] + red1[3]) / (float)W;

    float q = 0.f;
    #pragma unroll
    for (int e = 0; e < E; e++) { float d = v[e] - mean; q += d * d; }
    #pragma unroll
    for (int off = 32; off; off >>= 1) q += __shfl_xor(q, off, 64);
    if (lane == 0) red2[wid] = q;
    __syncthreads();
    const float var = (red2[0] + red2[1] + red2[2] + red2[3]) / (float)W;
    const float rstd = rsqrtf(var + 1e-5f);

    const int c0 = threadIdx.x * E;
    float o[E];
    #pragma unroll
    for (int e = 0; e < E; e++) {
        float ov = (v[e] - mean) * rstd * g[c0 + e] + bt[c0 + e];
        if (RELU) ov = ov > 0.f ? ov : 0.f;
        o[e] = ov;
    }
    if (OUTBF16) {
        ushort* op = (ushort*)out + (size_t)row * W + c0;
        unsigned int pk[E / 2];
        #pragma unroll
        for (int p = 0; p < E / 2; p++)
            pk[p] = ((unsigned int)f2b(o[2 * p])) | (((unsigned int)f2b(o[2 * p + 1])) << 16);
        if (E == 8) *reinterpret_cast<uint4*>(op) = *(uint4*)pk;
        else        *reinterpret_cast<uint2*>(op) = *(uint2*)pk;
    } else {
        float* op = (float*)out + (size_t)row * W + c0;
        #pragma unroll
        for (int p = 0; p < E / 4; p++)
            reinterpret_cast<float4*>(op)[p] = ((float4*)o)[p];
    }
}

extern "C" void kernel_launch(void* const* d_in, const int* in_sizes, int n_in,
                              void* d_out, int out_size, void* d_ws, size_t ws_size,
                              hipStream_t stream) {
    const float* x    = (const float*)d_in[0];
    const float* ipw  = (const float*)d_in[1];
    const float* ipb  = (const float*)d_in[2];
    const float* outw = (const float*)d_in[3];
    const float* outb = (const float*)d_in[4];
    const float* wg1w = (const float*)d_in[5];
    const float* wg1b = (const float*)d_in[6];
    const float* wg2w = (const float*)d_in[7];
    const float* wg2b = (const float*)d_in[8];
    const float* wg3w = (const float*)d_in[9];
    const float* wg3b = (const float*)d_in[10];
    const float* r1w  = (const float*)d_in[11];
    const float* r1b  = (const float*)d_in[12];
    const float* ln1g = (const float*)d_in[13];
    const float* ln1b = (const float*)d_in[14];
    const float* r2w  = (const float*)d_in[15];
    const float* r2b  = (const float*)d_in[16];
    const float* ln2g = (const float*)d_in[17];
    const float* ln2b = (const float*)d_in[18];

    char* ws = (char*)d_ws;
    // STABLE weight region (never aliased by activations):
    ushort* w_ip  = (ushort*)(ws + 0);          // 3072x1024 bf16 (6 MB)
    float*  zbias = (float*) (ws + 6291456);    // 4 KB (stable gap)
    float*  b1p   = (float*) (ws + 6295552);    // 4 KB
    float*  b_r1c = (float*) (ws + 6299648);    // 8 KB
    ushort* w_g1  = (ushort*)(ws + 8388608);    // 1024x3072
    ushort* w_g2  = (ushort*)(ws + 14680064);   // 512x1024
    ushort* w_r1  = (ushort*)(ws + 15728640);   // 2048x1024
    ushort* w_r2  = (ushort*)(ws + 19922944);   // 1024x2048
    char* R1 = ws + 24117248;                   // 100.7 MB: xb -> o_att -> ln1out
    char* R2 = ws + 124780544;                  // qkv -> subdivided (post-attention)

    ushort* xb       = (ushort*)R1;
    ushort* qkv      = (ushort*)R2;
    ushort* o_att    = (ushort*)R1;                    // [16384, 3072] == o_flat
    ushort* h1       = (ushort*)(R2 + 0);              // 33.5 MB
    ushort* h2       = (ushort*)(R2 + 33554432);       // 16.8 MB
    ushort* wsum_o   = (ushort*)(R2 + 50331648);       // 33.5 MB  (gated sum of o)
    ushort* r1out    = (ushort*)(R2 + 117440512);      // 67 MB
    ushort* r2out    = (ushort*)(R2 + 184549376);      // 33.5 MB
    ushort* w1p      = (ushort*)(R2 + 218103808);      // 6.3 MB  W1' [1024,3072]
    ushort* w_outT   = (ushort*)(R2 + 224395264);      // 2.1 MB  out_w^T bf16
    ushort* w_r1c    = (ushort*)(R2 + 226500608);      // 4.2 MB  (r1_w@out_w) [2048,1024]
    ushort* ln1out   = (ushort*)R1;                    // overwrites o_att (dead)

    // 132 KiB dynamic LDS (main loop 128K, epilogue 256x258 bf16)
    const int ldsBytes = 256 * CPAD * 2;   // 132096
    (void)hipFuncSetAttribute((const void*)gemm256<0>, hipFuncAttributeMaxDynamicSharedMemorySize, ldsBytes);
    (void)hipFuncSetAttribute((const void*)gemm256<1>, hipFuncAttributeMaxDynamicSharedMemorySize, ldsBytes);

    // converts: x (big) + fused weight converts (also zeros zbias, stable region)
    cvt_f32_bf16<<<49152, 256, 0, stream>>>(x, xb, (long)49152 * 1024);
    cvt_weights<<<10752, 256, 0, stream>>>(ipw, wg1w, wg2w, r1w, r2w,
                                           w_ip, w_g1, w_g2, w_r1, w_r2, zbias);

    // QKV + attention
    gemm256<0><<<192 * 12, 512, ldsBytes, stream>>>(xb, w_ip, ipb, qkv, 49152, 3072, 1024);
    attn_kernel<<<32768, 256, 0, stream>>>(qkv, o_att);

    // ---- weight prep for folded paths (qkv region now dead) ----
    transpose_cvt<<<1024, 256, 0, stream>>>(outw, w_outT);
    gemm_bt<0><<<dim3(64, 3), 256, 0, stream>>>(w_g1, w_outT, zbias, w1p,
                                                1024, 1024, 1024, 3072, 1024, 3072, 1024, 1024);
    bias1_kernel<<<256, 256, 0, stream>>>(wg1w, wg1b, outb, b1p);
    gemm_bt<0><<<dim3(128, 1), 256, 0, stream>>>(w_r1, w_outT, zbias, w_r1c,
                                                 2048, 1024, 1024, 1024, 1024, 1024, 0, 0);
    biasfold_kernel<<<512, 256, 0, stream>>>(r1w, outb, r1b, b_r1c, 1024);

    // gate MLP on o directly: h1 = relu(o_flat @ W1'^T + b1')
    gemm256<1><<<64 * 4, 512, ldsBytes, stream>>>(o_att, w1p, b1p, h1, 16384, 1024, 3072);
    gemm256<1><<<64 * 2, 512, ldsBytes, stream>>>(h1, w_g2, wg2b, h2, 16384, 512, 1024);
    gate_kernel<<<4096, 256, 0, stream>>>(h2, wg3w, wg3b, o_att, wsum_o);

    // refiner with folded out-proj: r1out = wsum_o @ (r1_w@out_w)^T + b_r1c
    gemm256<0><<<64 * 8, 512, ldsBytes, stream>>>(wsum_o, w_r1c, b_r1c, r1out, 16384, 2048, 1024);
    ln_kernel<2048, 1, 1><<<16384, 256, 0, stream>>>(r1out, ln1g, ln1b, ln1out);
    gemm256<0><<<64 * 4, 512, ldsBytes, stream>>>(ln1out, w_r2, r2b, r2out, 16384, 1024, 2048);
    ln_kernel<1024, 0, 0><<<16384, 256, 0, stream>>>(r2out, ln2g, ln2b, d_out);
}

// Round 13
// 821.770 us; speedup vs baseline: 1.0596x; 1.0060x over previous
//
#include <hip/hip_runtime.h>
#include <hip/hip_bf16.h>

// Problem constants
#define BB   16384
#define NBR  3
#define DD   1024
#define HH   8
#define HDD  128

typedef __attribute__((ext_vector_type(8))) short short8;
typedef __attribute__((ext_vector_type(4))) float f32x4;

__device__ __forceinline__ float b2f(ushort u) {
    union { unsigned int i; float f; } x; x.i = ((unsigned int)u) << 16; return x.f;
}
__device__ __forceinline__ ushort f2b(float f) {
    union { __hip_bfloat16 h; ushort u; } x; x.h = __float2bfloat16(f); return x.u;
}

// ---------------- fp32 -> bf16 convert (x input) ----------------
__global__ __launch_bounds__(256) void cvt_f32_bf16(const float* __restrict__ in,
                                                    ushort* __restrict__ out, long n) {
    long i = ((long)blockIdx.x * 256 + threadIdx.x) * 4;
    if (i + 4 > n) return;
    float4 v = *reinterpret_cast<const float4*>(in + i);
    unsigned int a = ((unsigned int)f2b(v.x)) | (((unsigned int)f2b(v.y)) << 16);
    unsigned int b = ((unsigned int)f2b(v.z)) | (((unsigned int)f2b(v.w)) << 16);
    uint2 p; p.x = a; p.y = b;
    *reinterpret_cast<uint2*>(out + i) = p;
}

// ---------------- fused weight converts (5 segments) + zbias zero ----------------
// zbias lives in the STABLE weight region (never aliased by activations).
__global__ __launch_bounds__(256) void cvt_weights(const float* __restrict__ ipw,
                                                   const float* __restrict__ wg1w,
                                                   const float* __restrict__ wg2w,
                                                   const float* __restrict__ r1w,
                                                   const float* __restrict__ r2w,
                                                   ushort* __restrict__ w_ip,
                                                   ushort* __restrict__ w_g1,
                                                   ushort* __restrict__ w_g2,
                                                   ushort* __restrict__ w_r1,
                                                   ushort* __restrict__ w_r2,
                                                   float* __restrict__ zbias) {
    if (blockIdx.x == 0) {
        float4 z = {0.f, 0.f, 0.f, 0.f};
        ((float4*)zbias)[threadIdx.x] = z;     // 1024 floats
    }
    long idx = (long)blockIdx.x * 256 + threadIdx.x;   // float4 units
    const float* src; ushort* dst;
    if (idx < 786432)                    { src = ipw;  dst = w_ip; }
    else if ((idx -= 786432) < 786432)   { src = wg1w; dst = w_g1; }
    else if ((idx -= 786432) < 131072)   { src = wg2w; dst = w_g2; }
    else if ((idx -= 131072) < 524288)   { src = r1w;  dst = w_r1; }
    else { idx -= 524288; if (idx >= 524288) return; src = r2w; dst = w_r2; }
    float4 v = ((const float4*)src)[idx];
    uint2 p;
    p.x = ((unsigned int)f2b(v.x)) | (((unsigned int)f2b(v.y)) << 16);
    p.y = ((unsigned int)f2b(v.z)) | (((unsigned int)f2b(v.w)) << 16);
    ((uint2*)dst)[idx] = p;
}

// ---------------- fp32 [1024,1024] transpose -> bf16 ----------------
__global__ __launch_bounds__(256) void transpose_cvt(const float* __restrict__ in,
                                                     ushort* __restrict__ out) {
    __shared__ float t[32][33];
    const int bx = blockIdx.x & 31, by = blockIdx.x >> 5;
    const int tx = threadIdx.x & 31, ty = threadIdx.x >> 5;   // 32x8
    #pragma unroll
    for (int i = 0; i < 4; i++)
        t[ty + i * 8][tx] = in[(size_t)(by * 32 + ty + i * 8) * 1024 + bx * 32 + tx];
    __syncthreads();
    #pragma unroll
    for (int i = 0; i < 4; i++)
        out[(size_t)(bx * 32 + ty + i * 8) * 1024 + by * 32 + tx] = f2b(t[tx][ty + i * 8]);
}

// ---------------- merged bias folds: b1p (1024 rows) + b_r1c (2048 rows) ----------------
// gw in [0,1024):   b1p[gw]  = wg1_b[gw] + sum_e outb[e]*(wg1w[gw,e]+wg1w[gw,e+1024]+wg1w[gw,e+2048])
// gw in [1024,3072): b_r1c[o] = r1_b[o]  + sum_e outb[e]*r1w[o,e]
__global__ __launch_bounds__(256) void bias_prep(const float* __restrict__ wg1w,
                                                 const float* __restrict__ wg1b,
                                                 const float* __restrict__ outb,
                                                 float* __restrict__ b1p,
                                                 const float* __restrict__ r1w,
                                                 const float* __restrict__ r1b,
                                                 float* __restrict__ b_r1c) {
    const int gw = blockIdx.x * 4 + (threadIdx.x >> 6);
    const int lane = threadIdx.x & 63;
    if (gw < 1024) {
        const float* wr = wg1w + (size_t)gw * 3072;
        float s = 0.f;
        for (int e = lane; e < 1024; e += 64)
            s += outb[e] * (wr[e] + wr[e + 1024] + wr[e + 2048]);
        #pragma unroll
        for (int off = 32; off; off >>= 1) s += __shfl_xor(s, off, 64);
        if (lane == 0) b1p[gw] = s + wg1b[gw];
    } else {
        const int o = gw - 1024;
        const float* wr = r1w + (size_t)o * 1024;
        float s = 0.f;
        for (int e = lane; e < 1024; e += 64) s += outb[e] * wr[e];
        #pragma unroll
        for (int off = 32; off; off >>= 1) s += __shfl_xor(s, off, 64);
        if (lane == 0) b_r1c[o] = s + r1b[o];
    }
}

// =====================================================================
// 256x256 GEMM: C[M,N] = A[M,K] @ Bt[N,K]^T + bias
// 512 threads (8 waves, 2x4), BK=64, double-buffered 128KiB LDS,
// staggered prefetch, counted vmcnt, raw barriers, XOR-swizzled LDS,
// setprio, XCD swizzle, LDS-staged epilogue, pipelined ds_reads.
// THIS ROUND: trailing barrier removed (4 barriers/K-tile, was 5) —
// STAGE(0) moved after the entry barrier so the entry barrier alone
// protects buf reuse; explicit barrier before the epilogue overwrite.
// EPI: 0 = bf16 out, 1 = bf16 out + relu
// =====================================================================
#define CPAD 258
template<int EPI>
__global__ __launch_bounds__(512, 2)
void gemm256(const ushort* __restrict__ A, const ushort* __restrict__ Bt,
             const float* __restrict__ bias, void* __restrict__ Cout,
             int M, int N, int K) {
    extern __shared__ ushort lds[];   // main loop: 4x16384; epilogue: [256][258] C tile

    const int tid  = threadIdx.x;     // 0..511
    const int wid  = tid >> 6;        // 0..7
    const int lane = tid & 63;
    // XCD-aware bijective swizzle (grid always divisible by 8)
    const int cpx  = gridDim.x >> 3;
    const int bid  = (blockIdx.x & 7) * cpx + (blockIdx.x >> 3);
    const int nbn  = N >> 8;
    const int bm   = bid / nbn;
    const int bn   = bid % nbn;
    const long m0  = (long)bm * 256;
    const long n0  = (long)bn * 256;
    const int NT   = K >> 6;          // K-tiles (even: 16/32/48)

    // ---- staging addresses
    const int srow = tid >> 3;                         // 0..63
    const int kel  = (((tid & 7) ^ (srow & 7)) << 3);  // pre-swizzled k element offset
    const int widEl = wid * 512;                       // wave-uniform LDS element base

    const ushort* gA[2][2];
    const ushort* gB[2][2];
    #pragma unroll
    for (int c = 0; c < 2; c++)
        #pragma unroll
        for (int j = 0; j < 2; j++) {
            gA[c][j] = A  + (size_t)(m0 + c * 128 + j * 64 + srow) * K + kel;
            gB[c][j] = Bt + (size_t)(n0 + c * 128 + j * 64 + srow) * K + kel;
        }

    // ---- fragment read offsets (per lane)
    const int wr = wid >> 2, wc = wid & 3;   // 2x4 waves; per-wave C block 128x64
    const int lm15 = lane & 15;
    int aoff[8];
    #pragma unroll
    for (int m = 0; m < 8; m++) aoff[m] = (wr * 128 + m * 16 + lm15) * 64;
    int boff[4];
    #pragma unroll
    for (int c = 0; c < 4; c++) boff[c] = (wc * 64 + c * 16 + lm15) * 64;
    const int kbr[2] = {
        (((0 << 6) | ((lane >> 4) << 4)) ^ ((lane & 7) << 4)) >> 1,
        (((1 << 6) | ((lane >> 4) << 4)) ^ ((lane & 7) << 4)) >> 1
    };

    f32x4 acc[8][4];
    #pragma unroll
    for (int m = 0; m < 8; m++)
        #pragma unroll
        for (int c = 0; c < 4; c++) { f32x4 z = {0.f, 0.f, 0.f, 0.f}; acc[m][c] = z; }

    short8 af[8], af2[8], bf[2], bf2[2];

#define STAGE(C, PB, TT) { \
    const ushort* _g0; const ushort* _g1; int _b; \
    if ((C) < 2) { _g0 = gA[(C)][0] + (TT) * 64; _g1 = gA[(C)][1] + (TT) * 64; \
                   _b = (PB) * 16384 + (C) * 8192 + widEl; } \
    else         { _g0 = gB[(C) - 2][0] + (TT) * 64; _g1 = gB[(C) - 2][1] + (TT) * 64; \
                   _b = 32768 + (PB) * 16384 + ((C) - 2) * 8192 + widEl; } \
    __builtin_amdgcn_global_load_lds((const __attribute__((address_space(1))) void*)_g0, \
        (__attribute__((address_space(3))) void*)&lds[_b], 16, 0, 0); \
    __builtin_amdgcn_global_load_lds((const __attribute__((address_space(1))) void*)_g1, \
        (__attribute__((address_space(3))) void*)&lds[_b + 4096], 16, 0, 0); }

#define READ_A(DST, P, KK) { \
    _Pragma("unroll") \
    for (int _m = 0; _m < 8; _m++) \
        DST[_m] = *(const short8*)&lds[(P) * 16384 + aoff[_m] + kbr[KK]]; }

#define READ_B2(DST, P, KK, C0) { \
    DST[0] = *(const short8*)&lds[32768 + (P) * 16384 + boff[(C0)] + kbr[KK]]; \
    DST[1] = *(const short8*)&lds[32768 + (P) * 16384 + boff[(C0) + 1] + kbr[KK]]; }

#define MFMA8x2(AF, BF, C0) { \
    _Pragma("unroll") \
    for (int _m = 0; _m < 8; _m++) { \
        acc[_m][(C0)]     = __builtin_amdgcn_mfma_f32_16x16x32_bf16(AF[_m], BF[0], acc[_m][(C0)], 0, 0, 0); \
        acc[_m][(C0) + 1] = __builtin_amdgcn_mfma_f32_16x16x32_bf16(AF[_m], BF[1], acc[_m][(C0) + 1], 0, 0, 0); } }

// One K-tile: 4 MFMA phases, 4 barriers (entry + 3 mid; no trailing).
// Entry vmcnt(0) waits exactly this tile's 8 staging loads (no younger
// loads outstanding at that point). STAGE(0) for tile T+1 is issued
// AFTER the entry barrier: all reads of buf P^1 (tile T-1's data) were
// register-consumed before any wave crossed this barrier.
#define TILE_STEP(P, T, PRE) { \
    asm volatile("s_waitcnt vmcnt(0)" ::: "memory"); \
    __builtin_amdgcn_s_barrier(); \
    asm volatile("" ::: "memory"); \
    __builtin_amdgcn_sched_barrier(0); \
    if (PRE) STAGE(0, (P) ^ 1, (T) + 1); \
    READ_A(af, P, 0); \
    READ_B2(bf, P, 0, 0); \
    __builtin_amdgcn_s_setprio(1); MFMA8x2(af, bf, 0); __builtin_amdgcn_s_setprio(0); \
    if (PRE) STAGE(1, (P) ^ 1, (T) + 1); \
    READ_B2(bf2, P, 0, 2); \
    __builtin_amdgcn_s_barrier(); \
    __builtin_amdgcn_s_setprio(1); MFMA8x2(af, bf2, 2); __builtin_amdgcn_s_setprio(0); \
    if (PRE) STAGE(2, (P) ^ 1, (T) + 1); \
    READ_A(af2, P, 1); \
    READ_B2(bf, P, 1, 0); \
    __builtin_amdgcn_s_barrier(); \
    __builtin_amdgcn_s_setprio(1); MFMA8x2(af2, bf, 0); __builtin_amdgcn_s_setprio(0); \
    if (PRE) STAGE(3, (P) ^ 1, (T) + 1); \
    READ_B2(bf2, P, 1, 2); \
    __builtin_amdgcn_s_barrier(); \
    __builtin_amdgcn_s_setprio(1); MFMA8x2(af2, bf2, 2); __builtin_amdgcn_s_setprio(0); }

    // prologue: stage all of tile 0 into buf0
    STAGE(0, 0, 0); STAGE(1, 0, 0); STAGE(2, 0, 0); STAGE(3, 0, 0);

    int t = 0;
    for (; t + 2 < NT; t += 2) {
        TILE_STEP(0, t, true);
        TILE_STEP(1, t + 1, true);
    }
    TILE_STEP(0, t, true);
    TILE_STEP(1, t + 1, false);

#undef TILE_STEP
#undef MFMA8x2
#undef READ_B2
#undef READ_A
#undef STAGE

    // barrier before overwriting LDS with C data: guarantees every wave's
    // final-phase ds_reads are register-consumed (lgkm waited before its MFMA).
    __builtin_amdgcn_s_barrier();
    asm volatile("" ::: "memory");

    // ---- epilogue via LDS ----
    // Fragment layout: row = wr*128 + m*16 + (lane>>4)*4 + j, col = wc*64 + c*16 + (lane&15).
    const int l16 = lane >> 4;
    #pragma unroll
    for (int c = 0; c < 4; c++) {
        const int colc = wc * 64 + c * 16 + lm15;
        const float bc = bias[n0 + colc];
        #pragma unroll
        for (int m = 0; m < 8; m++) {
            const int rowb = wr * 128 + m * 16 + l16 * 4;
            #pragma unroll
            for (int j = 0; j < 4; j++) {
                float v = acc[m][c][j] + bc;
                if (EPI == 1) v = v > 0.f ? v : 0.f;
                lds[(rowb + j) * CPAD + colc] = f2b(v);
            }
        }
    }
    __syncthreads();
    // coalesced copy-out: each wave writes two full 512B row segments per instr
    {
        const int r0 = tid >> 5;          // 0..15
        const int c0 = (tid & 31) * 8;    // 0..248
        #pragma unroll
        for (int it = 0; it < 16; it++) {
            const int row = it * 16 + r0;
            short8 val = *(const short8*)&lds[row * CPAD + c0];
            *reinterpret_cast<short8*>(&((ushort*)Cout)[(m0 + row) * (long)N + n0 + c0]) = val;
        }
    }
}

// ---------------- 128x128 bf16 GEMM with lda/ldb/ldc + batch (blockIdx.y) ----------------
template<int EPI>
__global__ __launch_bounds__(256, 2)
void gemm_bt(const ushort* __restrict__ A, const ushort* __restrict__ Bt,
             const float* __restrict__ bias, void* __restrict__ Cout,
             int M, int N, int K, int lda, int ldb, int ldc, int sA, int sC) {
    __shared__ ushort As[128 * 64];
    __shared__ ushort Bs[128 * 64];
    const int tid  = threadIdx.x;
    const int wid  = tid >> 6;
    const int lane = tid & 63;
    const int cpx  = gridDim.x >> 3;
    const int bid  = (blockIdx.x & 7) * cpx + (blockIdx.x >> 3);
    const int nbn  = N >> 7;
    const int bm   = bid / nbn;
    const int bn   = bid % nbn;
    const long m0  = (long)bm * 128;
    const long n0  = (long)bn * 128;

    A += (size_t)blockIdx.y * sA;
    const long cOff = (long)blockIdx.y * sC;

    const int srow = tid >> 3;
    const int scol = (tid & 7) << 3;
    const ushort* gA = A  + (m0 + srow) * (long)lda + scol;
    const ushort* gB = Bt + (n0 + srow) * (long)ldb + scol;

    f32x4 acc[4][4];
    #pragma unroll
    for (int i = 0; i < 4; i++)
        #pragma unroll
        for (int j = 0; j < 4; j++) { f32x4 z = {0.f, 0.f, 0.f, 0.f}; acc[i][j] = z; }

    const int wr = wid >> 1, wc = wid & 1;
    const int kits = K >> 6;

    for (int kt = 0; kt < kits; ++kt) {
        const ushort* pA = gA + kt * 64;
        const ushort* pB = gB + kt * 64;
        #pragma unroll
        for (int i = 0; i < 4; i++) {
            __builtin_amdgcn_global_load_lds(
                (const __attribute__((address_space(1))) void*)(pA + (long)i * 32 * lda),
                (__attribute__((address_space(3))) void*)&As[(i * 32 + wid * 8) * 64],
                16, 0, 0);
        }
        #pragma unroll
        for (int i = 0; i < 4; i++) {
            __builtin_amdgcn_global_load_lds(
                (const __attribute__((address_space(1))) void*)(pB + (long)i * 32 * ldb),
                (__attribute__((address_space(3))) void*)&Bs[(i * 32 + wid * 8) * 64],
                16, 0, 0);
        }
        __syncthreads();
        #pragma unroll
        for (int kk = 0; kk < 2; kk++) {
            const int ko = kk * 32 + (lane >> 4) * 8;
            short8 af[4], bf[4];
            #pragma unroll
            for (int m = 0; m < 4; m++)
                af[m] = *(const short8*)&As[(wr * 64 + m * 16 + (lane & 15)) * 64 + ko];
            #pragma unroll
            for (int n = 0; n < 4; n++)
                bf[n] = *(const short8*)&Bs[(wc * 64 + n * 16 + (lane & 15)) * 64 + ko];
            #pragma unroll
            for (int m = 0; m < 4; m++)
                #pragma unroll
                for (int n = 0; n < 4; n++)
                    acc[m][n] = __builtin_amdgcn_mfma_f32_16x16x32_bf16(af[m], bf[n], acc[m][n], 0, 0, 0);
        }
        __syncthreads();
    }

    #pragma unroll
    for (int n = 0; n < 4; n++) {
        const long c = n0 + wc * 64 + n * 16 + (lane & 15);
        const float bc = bias[c];
        #pragma unroll
        for (int m = 0; m < 4; m++) {
            const long r = m0 + wr * 64 + m * 16 + (lane >> 4) * 4;
            #pragma unroll
            for (int j = 0; j < 4; j++) {
                float v = acc[m][n][j] + bc;
                if (EPI == 1) v = v > 0.f ? v : 0.f;
                ((ushort*)Cout)[(r + j) * (long)ldc + cOff + c] = f2b(v);
            }
        }
    }
}

// ---------------- tiny attention over NB=3 tokens, ONE WAVE per (b,h) ----------------
__global__ __launch_bounds__(256) void attn_kernel(const ushort* __restrict__ qkv,
                                                   ushort* __restrict__ o) {
    const int w    = (blockIdx.x * 256 + threadIdx.x) >> 6;
    const int lane = threadIdx.x & 63;
    const int b = w >> 3, h = w & 7;
    const ushort* base = qkv + (size_t)b * (3 * 3072) + h * HDD + lane * 2;

    float q[3][2], k[3][2], v[3][2];
    #pragma unroll
    for (int i = 0; i < 3; i++) {
        unsigned int qu = *(const unsigned int*)(base + i * 3072);
        unsigned int ku = *(const unsigned int*)(base + i * 3072 + 1024);
        unsigned int vu = *(const unsigned int*)(base + i * 3072 + 2048);
        q[i][0] = b2f((ushort)(qu & 0xffff)); q[i][1] = b2f((ushort)(qu >> 16));
        k[i][0] = b2f((ushort)(ku & 0xffff)); k[i][1] = b2f((ushort)(ku >> 16));
        v[i][0] = b2f((ushort)(vu & 0xffff)); v[i][1] = b2f((ushort)(vu >> 16));
    }

    float s[3][3];
    #pragma unroll
    for (int i = 0; i < 3; i++)
        #pragma unroll
        for (int j = 0; j < 3; j++)
            s[i][j] = q[i][0] * k[j][0] + q[i][1] * k[j][1];

    #pragma unroll
    for (int off = 32; off; off >>= 1)
        #pragma unroll
        for (int i = 0; i < 3; i++)
            #pragma unroll
            for (int j = 0; j < 3; j++)
                s[i][j] += __shfl_xor(s[i][j], off, 64);

    const float sc = 0.08838834764831845f;
    float a[3][3];
    #pragma unroll
    for (int i = 0; i < 3; i++) {
        float l0 = s[i][0] * sc, l1 = s[i][1] * sc, l2 = s[i][2] * sc;
        float mx = fmaxf(fmaxf(l0, l1), l2);
        float e0 = __expf(l0 - mx), e1 = __expf(l1 - mx), e2 = __expf(l2 - mx);
        float inv = 1.f / (e0 + e1 + e2);
        a[i][0] = e0 * inv; a[i][1] = e1 * inv; a[i][2] = e2 * inv;
    }

    ushort* ob = o + (size_t)b * 3072 + h * HDD + lane * 2;
    #pragma unroll
    for (int i = 0; i < 3; i++) {
        float o0 = a[i][0] * v[0][0] + a[i][1] * v[1][0] + a[i][2] * v[2][0];
        float o1 = a[i][0] * v[0][1] + a[i][1] * v[1][1] + a[i][2] * v[2][1];
        unsigned int pk = ((unsigned int)f2b(o0)) | (((unsigned int)f2b(o1)) << 16);
        *(unsigned int*)(ob + i * 1024) = pk;
    }
}

// ---------------- wg3 logits + softmax + weighted branch sum (over o) ----------------
__global__ __launch_bounds__(256) void gate_kernel(const ushort* __restrict__ h2,
                                                   const float* __restrict__ w3,
                                                   const float* __restrict__ b3,
                                                   const ushort* __restrict__ att,
                                                   ushort* __restrict__ weighted) {
    const int gw = (blockIdx.x * 256 + threadIdx.x) >> 6;
    const int lane = threadIdx.x & 63;
    if (gw >= BB) return;

    const ushort* hr = h2 + (size_t)gw * 512 + lane * 8;
    short8 hv = *(const short8*)hr;
    float hf[8];
    #pragma unroll
    for (int d = 0; d < 8; d++) hf[d] = b2f((ushort)hv[d]);

    float dot[3];
    #pragma unroll
    for (int s = 0; s < 3; s++) {
        const float* wr = w3 + s * 512 + lane * 8;
        float4 wa = *(const float4*)wr;
        float4 wb = *(const float4*)(wr + 4);
        dot[s] = hf[0] * wa.x + hf[1] * wa.y + hf[2] * wa.z + hf[3] * wa.w
               + hf[4] * wb.x + hf[5] * wb.y + hf[6] * wb.z + hf[7] * wb.w;
    }
    #pragma unroll
    for (int off = 32; off; off >>= 1)
        #pragma unroll
        for (int s = 0; s < 3; s++) dot[s] += __shfl_xor(dot[s], off, 64);

    float l0 = dot[0] + b3[0], l1 = dot[1] + b3[1], l2 = dot[2] + b3[2];
    float mx = fmaxf(fmaxf(l0, l1), l2);
    float e0 = __expf(l0 - mx), e1 = __expf(l1 - mx), e2 = __expf(l2 - mx);
    float inv = 1.f / (e0 + e1 + e2);
    float w0 = e0 * inv, w1 = e1 * inv, w2 = e2 * inv;

    const ushort* ab = att + (size_t)gw * 3072;
    ushort* wb = weighted + (size_t)gw * 1024;
    #pragma unroll
    for (int i = 0; i < 2; i++) {
        int d0 = (i * 64 + lane) * 8;
        short8 a0 = *(const short8*)(ab + d0);
        short8 a1 = *(const short8*)(ab + 1024 + d0);
        short8 a2 = *(const short8*)(ab + 2048 + d0);
        short8 r;
        #pragma unroll
        for (int d = 0; d < 8; d++) {
            float v = w0 * b2f((ushort)a0[d]) + w1 * b2f((ushort)a1[d]) + w2 * b2f((ushort)a2[d]);
            r[d] = (short)f2b(v);
        }
        *(short8*)(wb + d0) = r;
    }
}

// ---------------- LayerNorm over W cols (bf16 input), one block per row ----------------
template<int W, int RELU, int OUTBF16>
__global__ __launch_bounds__(256) void ln_kernel(const ushort* __restrict__ in,
                                                 const float* __restrict__ g,
                                                 const float* __restrict__ bt,
                                                 void* __restrict__ out) {
    constexpr int E = W / 256;
    const int row = blockIdx.x;
    const ushort* xr = in + (size_t)row * W + threadIdx.x * E;

    float v[E];
    if (E == 8) {
        uint4 raw = *reinterpret_cast<const uint4*>(xr);
        const unsigned int* rw = (const unsigned int*)&raw;
        #pragma unroll
        for (int p = 0; p < 4; p++) {
            v[2 * p]     = b2f((ushort)(rw[p] & 0xffff));
            v[2 * p + 1] = b2f((ushort)(rw[p] >> 16));
        }
    } else {
        uint2 raw = *reinterpret_cast<const uint2*>(xr);
        const unsigned int* rw = (const unsigned int*)&raw;
        #pragma unroll
        for (int p = 0; p < 2; p++) {
            v[2 * p]     = b2f((ushort)(rw[p] & 0xffff));
            v[2 * p + 1] = b2f((ushort)(rw[p] >> 16));
        }
    }

    float s = 0.f;
    #pragma unroll
    for (int e = 0; e < E; e++) s += v[e];

    __shared__ float red1[4], red2[4];
    const int wid = threadIdx.x >> 6, lane = threadIdx.x & 63;
    #pragma unroll
    for (int off = 32; off; off >>= 1) s += __shfl_xor(s, off, 64);
    if (lane == 0) red1[wid] = s;
    __syncthreads();
    const float mean = (red1[0] + red1[1] + red1[2] + red1[3]) / (float)W;

    float q = 0.f;
    #pragma unroll
    for (int e = 0; e < E; e++) { float d = v[e] - mean; q += d * d; }
    #pragma unroll
    for (int off = 32; off; off >>= 1) q += __shfl_xor(q, off, 64);
    if (lane == 0) red2[wid] = q;
    __syncthreads();
    const float var = (red2[0] + red2[1] + red2[2] + red2[3]) / (float)W;
    const float rstd = rsqrtf(var + 1e-5f);

    const int c0 = threadIdx.x * E;
    float o[E];
    #pragma unroll
    for (int e = 0; e < E; e++) {
        float ov = (v[e] - mean) * rstd * g[c0 + e] + bt[c0 + e];
        if (RELU) ov = ov > 0.f ? ov : 0.f;
        o[e] = ov;
    }
    if (OUTBF16) {
        ushort* op = (ushort*)out + (size_t)row * W + c0;
        unsigned int pk[E / 2];
        #pragma unroll
        for (int p = 0; p < E / 2; p++)
            pk[p] = ((unsigned int)f2b(o[2 * p])) | (((unsigned int)f2b(o[2 * p + 1])) << 16);
        if (E == 8) *reinterpret_cast<uint4*>(op) = *(uint4*)pk;
        else        *reinterpret_cast<uint2*>(op) = *(uint2*)pk;
    } else {
        float* op = (float*)out + (size_t)row * W + c0;
        #pragma unroll
        for (int p = 0; p < E / 4; p++)
            reinterpret_cast<float4*>(op)[p] = ((float4*)o)[p];
    }
}

extern "C" void kernel_launch(void* const* d_in, const int* in_sizes, int n_in,
                              void* d_out, int out_size, void* d_ws, size_t ws_size,
                              hipStream_t stream) {
    const float* x    = (const float*)d_in[0];
    const float* ipw  = (const float*)d_in[1];
    const float* ipb  = (const float*)d_in[2];
    const float* outw = (const float*)d_in[3];
    const float* outb = (const float*)d_in[4];
    const float* wg1w = (const float*)d_in[5];
    const float* wg1b = (const float*)d_in[6];
    const float* wg2w = (const float*)d_in[7];
    const float* wg2b = (const float*)d_in[8];
    const float* wg3w = (const float*)d_in[9];
    const float* wg3b = (const float*)d_in[10];
    const float* r1w  = (const float*)d_in[11];
    const float* r1b  = (const float*)d_in[12];
    const float* ln1g = (const float*)d_in[13];
    const float* ln1b = (const float*)d_in[14];
    const float* r2w  = (const float*)d_in[15];
    const float* r2b  = (const float*)d_in[16];
    const float* ln2g = (const float*)d_in[17];
    const float* ln2b = (const float*)d_in[18];

    char* ws = (char*)d_ws;
    // STABLE weight region (never aliased by activations):
    ushort* w_ip  = (ushort*)(ws + 0);          // 3072x1024 bf16 (6 MB)
    float*  zbias = (float*) (ws + 6291456);    // 4 KB (stable gap)
    float*  b1p   = (float*) (ws + 6295552);    // 4 KB
    float*  b_r1c = (float*) (ws + 6299648);    // 8 KB
    ushort* w_g1  = (ushort*)(ws + 8388608);    // 1024x3072
    ushort* w_g2  = (ushort*)(ws + 14680064);   // 512x1024
    ushort* w_r1  = (ushort*)(ws + 15728640);   // 2048x1024
    ushort* w_r2  = (ushort*)(ws + 19922944);   // 1024x2048
    char* R1 = ws + 24117248;                   // 100.7 MB: xb -> o_att -> ln1out
    char* R2 = ws + 124780544;                  // qkv -> subdivided (post-attention)

    ushort* xb       = (ushort*)R1;
    ushort* qkv      = (ushort*)R2;
    ushort* o_att    = (ushort*)R1;                    // [16384, 3072] == o_flat
    ushort* h1       = (ushort*)(R2 + 0);              // 33.5 MB
    ushort* h2       = (ushort*)(R2 + 33554432);       // 16.8 MB
    ushort* wsum_o   = (ushort*)(R2 + 50331648);       // 33.5 MB  (gated sum of o)
    ushort* r1out    = (ushort*)(R2 + 117440512);      // 67 MB
    ushort* r2out    = (ushort*)(R2 + 184549376);      // 33.5 MB
    ushort* w1p      = (ushort*)(R2 + 218103808);      // 6.3 MB  W1' [1024,3072]
    ushort* w_outT   = (ushort*)(R2 + 224395264);      // 2.1 MB  out_w^T bf16
    ushort* w_r1c    = (ushort*)(R2 + 226500608);      // 4.2 MB  (r1_w@out_w) [2048,1024]
    ushort* ln1out   = (ushort*)R1;                    // overwrites o_att (dead)

    // 132 KiB dynamic LDS (main loop 128K, epilogue 256x258 bf16)
    const int ldsBytes = 256 * CPAD * 2;   // 132096
    (void)hipFuncSetAttribute((const void*)gemm256<0>, hipFuncAttributeMaxDynamicSharedMemorySize, ldsBytes);
    (void)hipFuncSetAttribute((const void*)gemm256<1>, hipFuncAttributeMaxDynamicSharedMemorySize, ldsBytes);

    // converts: x (big) + fused weight converts (also zeros zbias, stable region)
    cvt_f32_bf16<<<49152, 256, 0, stream>>>(x, xb, (long)49152 * 1024);
    cvt_weights<<<10752, 256, 0, stream>>>(ipw, wg1w, wg2w, r1w, r2w,
                                           w_ip, w_g1, w_g2, w_r1, w_r2, zbias);

    // QKV + attention
    gemm256<0><<<192 * 12, 512, ldsBytes, stream>>>(xb, w_ip, ipb, qkv, 49152, 3072, 1024);
    attn_kernel<<<32768, 256, 0, stream>>>(qkv, o_att);

    // ---- weight prep for folded paths (qkv region now dead) ----
    transpose_cvt<<<1024, 256, 0, stream>>>(outw, w_outT);
    gemm_bt<0><<<dim3(64, 3), 256, 0, stream>>>(w_g1, w_outT, zbias, w1p,
                                                1024, 1024, 1024, 3072, 1024, 3072, 1024, 1024);
    gemm_bt<0><<<dim3(128, 1), 256, 0, stream>>>(w_r1, w_outT, zbias, w_r1c,
                                                 2048, 1024, 1024, 1024, 1024, 1024, 0, 0);
    bias_prep<<<768, 256, 0, stream>>>(wg1w, wg1b, outb, b1p, r1w, r1b, b_r1c);

    // gate MLP on o directly: h1 = relu(o_flat @ W1'^T + b1')
    gemm256<1><<<64 * 4, 512, ldsBytes, stream>>>(o_att, w1p, b1p, h1, 16384, 1024, 3072);
    gemm256<1><<<64 * 2, 512, ldsBytes, stream>>>(h1, w_g2, wg2b, h2, 16384, 512, 1024);
    gate_kernel<<<4096, 256, 0, stream>>>(h2, wg3w, wg3b, o_att, wsum_o);

    // refiner with folded out-proj: r1out = wsum_o @ (r1_w@out_w)^T + b_r1c
    gemm256<0><<<64 * 8, 512, ldsBytes, stream>>>(wsum_o, w_r1c, b_r1c, r1out, 16384, 2048, 1024);
    ln_kernel<2048, 1, 1><<<16384, 256, 0, stream>>>(r1out, ln1g, ln1b, ln1out);
    gemm256<0><<<64 * 4, 512, ldsBytes, stream>>>(ln1out, w_r2, r2b, r2out, 16384, 1024, 2048);
    ln_kernel<1024, 0, 0><<<16384, 256, 0, stream>>>(r2out, ln2g, ln2b, d_out);
}